// Round 1
// baseline (1884.235 us; speedup 1.0000x reference)
//
#include <hip/hip_runtime.h>
#include <math.h>

#define DQ 2048
#define CDIM 512
#define NKEYS 256
#define KSEL 32

__device__ __forceinline__ bool rank_before(float as, int ai, float bs, int bi) {
  return (as > bs) || (as == bs && ai < bi);
}
static __device__ __forceinline__ float bf2f(unsigned int u) {
  union { unsigned int i; float f; } v; v.i = u << 16; return v.f;
}
static __device__ __forceinline__ unsigned int f2bf(float f) {
  union { float f; unsigned int i; } v; v.f = f;
  unsigned int r = v.i + 0x7fffu + ((v.i >> 16) & 1u);
  return r >> 16;
}

// ---------------- q = LN(X * Wq^T) fused (fp32 vector GEMM + groupwise LN) ----------------
__global__ __launch_bounds__(256) void qgemm_ln(
    const float* __restrict__ X, const float* __restrict__ W,
    const float* __restrict__ gamma, const float* __restrict__ beta,
    float* __restrict__ Q) {
  __shared__ float As[16 * 68];   // [k][m]
  __shared__ float Bs[16 * 132];  // [k][n]
  const int tid = threadIdx.x;
  const int m0 = blockIdx.x * 64, n0 = blockIdx.y * 128;
  const int tx = tid & 15, ty = tid >> 4;
  const int am = tid >> 2, ak = (tid & 3) * 4;
  const int bn = tid >> 1, bk = (tid & 1) * 8;
  float acc[4][8] = {};
  // software prefetch of first tile
  float4 av  = *(const float4*)&X[(size_t)(m0 + am) * CDIM + ak];
  float4 bv0 = *(const float4*)&W[(size_t)(n0 + bn) * CDIM + bk];
  float4 bv1 = *(const float4*)&W[(size_t)(n0 + bn) * CDIM + bk + 4];
  for (int kt = 0; kt < CDIM; kt += 16) {
    __syncthreads();
    As[(ak + 0) * 68 + am] = av.x; As[(ak + 1) * 68 + am] = av.y;
    As[(ak + 2) * 68 + am] = av.z; As[(ak + 3) * 68 + am] = av.w;
    Bs[(bk + 0) * 132 + bn] = bv0.x; Bs[(bk + 1) * 132 + bn] = bv0.y;
    Bs[(bk + 2) * 132 + bn] = bv0.z; Bs[(bk + 3) * 132 + bn] = bv0.w;
    Bs[(bk + 4) * 132 + bn] = bv1.x; Bs[(bk + 5) * 132 + bn] = bv1.y;
    Bs[(bk + 6) * 132 + bn] = bv1.z; Bs[(bk + 7) * 132 + bn] = bv1.w;
    __syncthreads();
    if (kt + 16 < CDIM) {  // prefetch next tile; latency hides behind compute
      av  = *(const float4*)&X[(size_t)(m0 + am) * CDIM + kt + 16 + ak];
      bv0 = *(const float4*)&W[(size_t)(n0 + bn) * CDIM + kt + 16 + bk];
      bv1 = *(const float4*)&W[(size_t)(n0 + bn) * CDIM + kt + 16 + bk + 4];
    }
    #pragma unroll
    for (int kk = 0; kk < 16; ++kk) {
      float4 a4  = *(const float4*)&As[kk * 68 + ty * 4];
      float4 b4a = *(const float4*)&Bs[kk * 132 + tx * 8];
      float4 b4b = *(const float4*)&Bs[kk * 132 + tx * 8 + 4];
      const float ar[4] = {a4.x, a4.y, a4.z, a4.w};
      const float br[8] = {b4a.x, b4a.y, b4a.z, b4a.w, b4b.x, b4b.y, b4b.z, b4b.w};
      #pragma unroll
      for (int i = 0; i < 4; ++i)
        #pragma unroll
        for (int j = 0; j < 8; ++j)
          acc[i][j] += ar[i] * br[j];
    }
  }
  float g[8], bta[8];
  #pragma unroll
  for (int j = 0; j < 8; ++j) { g[j] = gamma[tx * 8 + j]; bta[j] = beta[tx * 8 + j]; }
  #pragma unroll
  for (int i = 0; i < 4; ++i) {
    float s = 0.f, sq = 0.f;
    #pragma unroll
    for (int j = 0; j < 8; ++j) { s += acc[i][j]; sq += acc[i][j] * acc[i][j]; }
    #pragma unroll
    for (int m = 1; m < 16; m <<= 1) {
      s += __shfl_xor(s, m, 64);
      sq += __shfl_xor(sq, m, 64);
    }
    float mean = s * (1.0f / 128.0f);
    float var = sq * (1.0f / 128.0f) - mean * mean;
    float rs = 1.0f / sqrtf(var + 1e-5f);
    float o[8];
    #pragma unroll
    for (int j = 0; j < 8; ++j) o[j] = (acc[i][j] - mean) * rs * g[j] + bta[j];
    float* dst = &Q[(size_t)(m0 + ty * 4 + i) * DQ + n0 + tx * 8];
    *(float4*)dst = make_float4(o[0], o[1], o[2], o[3]);
    *(float4*)(dst + 4) = make_float4(o[4], o[5], o[6], o[7]);
  }
}

// ---------------- dots (tiled fp32 GEMM) + wave-parallel blocked bitonic top-32 ----------------
// Layout change vs previous version: after the GEMM, the 32x256 dot matrix is
// transposed through LDS (chunk-XOR swizzled, bank-conflict-free) so that each
// token's 256 scores live on 16 lanes x 16 contiguous elements. All 4 tokens of
// a wave then sort CONCURRENTLY in one generic bitonic-256: only 10 of 36 passes
// need cross-lane shuffles (vs 21 per token, x4 tokens serially, before).
__global__ __launch_bounds__(512, 6) void dots_sel(
    const float* __restrict__ Q, const float* __restrict__ keys,
    float* __restrict__ s1s, int* __restrict__ s1i) {
  const int hp = blockIdx.x;
  const int chunk = blockIdx.y;
  const int h = hp >> 1, p = hp & 1;
  const int t0 = chunk * 32;
  // Qs (32*132) + Bs (16*260) = 33536 B, aliased with Sd (32*264 = 33792 B)
  __shared__ __align__(16) float smem[32 * 264];
  float* Qs = smem;            // during GEMM
  float* Bs = smem + 32 * 132; // during GEMM
  float* Sd = smem;            // after GEMM (Qs/Bs dead)
  const int tid = threadIdx.x;
  const int w = tid >> 6, lane = tid & 63;
  {
    const int tok = tid >> 4, d0 = (tid & 15) * 8;
    const float* src = &Q[(size_t)(t0 + tok) * DQ + p * 1024 + h * 128 + d0];
    *(float4*)&Qs[tok * 132 + d0] = *(const float4*)src;
    *(float4*)&Qs[tok * 132 + d0 + 4] = *(const float4*)(src + 4);
  }
  const int bn = tid >> 1, bkh = (tid & 1) * 8;
  const float* kbase = keys + ((size_t)(h * NKEYS + bn) * 2 + p) * 128;
  float acc[4][4] = {};
  float4 b0 = *(const float4*)&kbase[bkh];
  float4 b1 = *(const float4*)&kbase[bkh + 4];
  for (int kt = 0; kt < 128; kt += 16) {
    __syncthreads();
    Bs[(bkh + 0) * 260 + bn] = b0.x; Bs[(bkh + 1) * 260 + bn] = b0.y;
    Bs[(bkh + 2) * 260 + bn] = b0.z; Bs[(bkh + 3) * 260 + bn] = b0.w;
    Bs[(bkh + 4) * 260 + bn] = b1.x; Bs[(bkh + 5) * 260 + bn] = b1.y;
    Bs[(bkh + 6) * 260 + bn] = b1.z; Bs[(bkh + 7) * 260 + bn] = b1.w;
    __syncthreads();
    if (kt + 16 < 128) {  // prefetch next key K-slab
      b0 = *(const float4*)&kbase[kt + 16 + bkh];
      b1 = *(const float4*)&kbase[kt + 16 + bkh + 4];
    }
    #pragma unroll
    for (int k4 = 0; k4 < 16; k4 += 4) {
      float4 a0 = *(const float4*)&Qs[(w * 4 + 0) * 132 + kt + k4];
      float4 a1 = *(const float4*)&Qs[(w * 4 + 1) * 132 + kt + k4];
      float4 a2 = *(const float4*)&Qs[(w * 4 + 2) * 132 + kt + k4];
      float4 a3 = *(const float4*)&Qs[(w * 4 + 3) * 132 + kt + k4];
      const float a0r[4] = {a0.x, a0.y, a0.z, a0.w};
      const float a1r[4] = {a1.x, a1.y, a1.z, a1.w};
      const float a2r[4] = {a2.x, a2.y, a2.z, a2.w};
      const float a3r[4] = {a3.x, a3.y, a3.z, a3.w};
      #pragma unroll
      for (int kk = 0; kk < 4; ++kk) {
        float4 b4 = *(const float4*)&Bs[(k4 + kk) * 260 + lane * 4];
        const float br[4] = {b4.x, b4.y, b4.z, b4.w};
        #pragma unroll
        for (int j = 0; j < 4; ++j) {
          acc[0][j] += a0r[kk] * br[j];
          acc[1][j] += a1r[kk] * br[j];
          acc[2][j] += a2r[kk] * br[j];
          acc[3][j] += a3r[kk] * br[j];
        }
      }
    }
  }
  // ---- transpose dots into Sd: token rows of 264 floats, 16B chunks XOR-swizzled
  // by (token&3). Row stride 264 words == 8 mod 32 -> both write (fixed i: full
  // chunk permutation of one row, contiguous 1KB) and read (analysis: all 8
  // bank-quads covered evenly) sit at the 8-words/bank ds_*_b128 floor.
  __syncthreads();  // all waves done reading Qs/Bs before overwrite
  #pragma unroll
  for (int i = 0; i < 4; ++i)
    *(float4*)&Sd[(w * 4 + i) * 264 + ((lane ^ i) << 2)] =
        make_float4(acc[i][0], acc[i][1], acc[i][2], acc[i][3]);
  __syncthreads();

  // ---- blocked re-read: lane group of 16 per token, 16 contiguous scores/lane
  const int i4 = lane >> 4;       // token sub-index within wave (== token&3)
  const int gl = lane & 15;       // lane within token group
  const int tokl = w * 4 + i4;    // local token row
  float s[16]; int id[16];
  #pragma unroll
  for (int j = 0; j < 4; ++j) {
    const int pc = ((gl << 2) + j) ^ i4;  // physical chunk (undo swizzle)
    const float4 v = *(const float4*)&Sd[tokl * 264 + (pc << 2)];
    s[4 * j + 0] = v.x; s[4 * j + 1] = v.y;
    s[4 * j + 2] = v.z; s[4 * j + 3] = v.w;
    id[4 * j + 0] = (gl << 4) + 4 * j + 0;
    id[4 * j + 1] = (gl << 4) + 4 * j + 1;
    id[4 * j + 2] = (gl << 4) + 4 * j + 2;
    id[4 * j + 3] = (gl << 4) + 4 * j + 3;
  }

  // ---- generic bitonic-256, descending, tie -> lower id. Element e = gl*16+r.
  // dir(e) at level K: (e & K) != 0 -> ascending pair order (matches prior code).
  #define CEL(A, B, DD)                                                        \
    {                                                                          \
      bool sw_ = (DD) ? rank_before(s[A], id[A], s[B], id[B])                  \
                      : rank_before(s[B], id[B], s[A], id[A]);                 \
      if (sw_) {                                                               \
        float tf_ = s[A]; s[A] = s[B]; s[B] = tf_;                             \
        int ti_ = id[A]; id[A] = id[B]; id[B] = ti_;                           \
      }                                                                        \
    }
  // in-register pass: partner r^L within the lane (L < 16)
  #define PASS_R(KK, LL)                                                       \
    _Pragma("unroll")                                                          \
    for (int r_ = 0; r_ < 16; ++r_)                                            \
      if (!(r_ & (LL))) {                                                      \
        const bool dd_ = ((((gl << 4) + r_) & (KK)) != 0);                     \
        CEL(r_, r_ | (LL), dd_);                                               \
      }
  // cross-lane pass: partner lane gl ^ (L/16), same r (L >= 16); xor mask < 16
  // so shuffles never leave the 16-lane token group.
  #define PASS_X(KK, LL)                                                       \
    {                                                                          \
      const bool dd_x = ((gl & ((KK) >> 4)) != 0);                             \
      const bool amHigh_ = ((gl & ((LL) >> 4)) != 0);                          \
      const bool flip_ = amHigh_ != dd_x;                                      \
      _Pragma("unroll")                                                        \
      for (int r_ = 0; r_ < 16; ++r_) {                                        \
        float os_ = __shfl_xor(s[r_], (LL) >> 4, 64);                          \
        int oi_ = __shfl_xor(id[r_], (LL) >> 4, 64);                           \
        bool take_ = rank_before(os_, oi_, s[r_], id[r_]) != flip_;            \
        if (take_) { s[r_] = os_; id[r_] = oi_; }                              \
      }                                                                        \
    }

  PASS_R(2, 1);
  PASS_R(4, 2); PASS_R(4, 1);
  PASS_R(8, 4); PASS_R(8, 2); PASS_R(8, 1);
  PASS_R(16, 8); PASS_R(16, 4); PASS_R(16, 2); PASS_R(16, 1);
  PASS_X(32, 16);
  PASS_R(32, 8); PASS_R(32, 4); PASS_R(32, 2); PASS_R(32, 1);
  PASS_X(64, 32); PASS_X(64, 16);
  PASS_R(64, 8); PASS_R(64, 4); PASS_R(64, 2); PASS_R(64, 1);
  PASS_X(128, 64); PASS_X(128, 32); PASS_X(128, 16);
  PASS_R(128, 8); PASS_R(128, 4); PASS_R(128, 2); PASS_R(128, 1);
  PASS_X(256, 128); PASS_X(256, 64); PASS_X(256, 32); PASS_X(256, 16);
  PASS_R(256, 8); PASS_R(256, 4); PASS_R(256, 2); PASS_R(256, 1);

  #undef CEL
  #undef PASS_R
  #undef PASS_X

  // top-32 = sorted positions 0..31 = lanes gl 0,1 (16 regs each)
  if (gl < 2) {
    const int inst = (t0 + tokl) * 16 + hp;
    #pragma unroll
    for (int j = 0; j < 4; ++j) {
      *(float4*)&s1s[(size_t)inst * KSEL + (gl << 4) + 4 * j] =
          make_float4(s[4 * j], s[4 * j + 1], s[4 * j + 2], s[4 * j + 3]);
      *(int4*)&s1i[(size_t)inst * KSEL + (gl << 4) + 4 * j] =
          make_int4(id[4 * j], id[4 * j + 1], id[4 * j + 2], id[4 * j + 3]);
    }
  }
}

// ---------------- stage-2: pruned 119-candidate bitonic top-32 + softmax ----------------
__constant__ unsigned short slot_ij[128] = {
  0,1,2,3,4,5,6,7,8,9,10,11,12,13,14,15,16,17,18,19,20,21,22,23,24,25,26,27,28,29,30,31,
  32,33,34,35,36,37,38,39,40,41,42,43,44,45,46,47,
  64,65,66,67,68,69,70,71,72,73,
  96,97,98,99,100,101,102,103,
  128,129,130,131,132,133,
  160,161,162,163,164,
  192,193,194,195,
  224,225,226,227,
  256,257,258,
  288,289,290,
  320,321, 352,353, 384,385, 416,417, 448,449, 480,481,
  512,544,576,608,640,672,704,736,768,800,832,864,896,928,960,992,
  0xFFFF,0xFFFF,0xFFFF,0xFFFF,0xFFFF,0xFFFF,0xFFFF,0xFFFF,0xFFFF
};

__global__ __launch_bounds__(256) void stage2_kernel(
    const float* __restrict__ s1s, const int* __restrict__ s1i,
    float* __restrict__ wgt, int* __restrict__ vidx) {
  const int th = blockIdx.x * 4 + (threadIdx.x >> 6);
  const int lane = threadIdx.x & 63;
  const int bx = th * 64;
  const int by = bx + 32;
  float s[2]; int id[2];
  #pragma unroll
  for (int r = 0; r < 2; ++r) {
    int sl = slot_ij[lane * 2 + r];
    if (sl != 0xFFFF) {
      s[r] = s1s[bx + (sl >> 5)] + s1s[by + (sl & 31)];
      id[r] = sl;
    } else {
      s[r] = -INFINITY; id[r] = 0x7fffffff;
    }
  }
  #define CE2(dd)                                                              \
    {                                                                          \
      bool sw = (dd) ? rank_before(s[0], id[0], s[1], id[1])                   \
                     : rank_before(s[1], id[1], s[0], id[0]);                  \
      if (sw) {                                                                \
        float ts = s[0]; s[0] = s[1]; s[1] = ts;                               \
        int ti = id[0]; id[0] = id[1]; id[1] = ti;                             \
      }                                                                        \
    }
  #define CROSS2(L, dd)                                                        \
    {                                                                          \
      bool amHigh = (lane & (L)) != 0;                                         \
      bool flip = amHigh != (dd);                                              \
      _Pragma("unroll")                                                        \
      for (int r = 0; r < 2; ++r) {                                            \
        float os = __shfl_xor(s[r], (L), 64);                                  \
        int oi = __shfl_xor(id[r], (L), 64);                                   \
        bool take = rank_before(os, oi, s[r], id[r]) != flip;                  \
        if (take) { s[r] = os; id[r] = oi; }                                   \
      }                                                                        \
    }
  { bool dd = (lane & 1) != 0; CE2(dd); }
  #pragma unroll
  for (int K = 4; K <= 128; K <<= 1) {
    bool dd = (lane & (K >> 1)) != 0;
    #pragma unroll
    for (int L = K >> 2; L >= 1; L >>= 1) CROSS2(L, dd);
    CE2(dd);
  }
  #undef CE2
  #undef CROSS2
  float smax = __shfl(s[0], 0, 64);
  float e0 = 0.f, e1 = 0.f;
  if (lane < 16) { e0 = expf(s[0] - smax); e1 = expf(s[1] - smax); }
  float part = e0 + e1;
  #pragma unroll
  for (int m = 1; m < 16; m <<= 1) part += __shfl_xor(part, m, 64);
  if (lane < 16) {
    int f0 = id[0], f1 = id[1];
    int vi0 = s1i[bx + (f0 >> 5)] * NKEYS + s1i[by + (f0 & 31)];
    int vi1 = s1i[bx + (f1 >> 5)] * NKEYS + s1i[by + (f1 & 31)];
    wgt[(size_t)th * KSEL + lane * 2] = e0 / part;
    wgt[(size_t)th * KSEL + lane * 2 + 1] = e1 / part;
    vidx[(size_t)th * KSEL + lane * 2] = vi0;
    vidx[(size_t)th * KSEL + lane * 2 + 1] = vi1;
  }
}

// ---------------- values fp32 -> bf16 (RNE) one-pass convert ----------------
__global__ __launch_bounds__(256) void convert_values(
    const float* __restrict__ values, unsigned int* __restrict__ vbf) {
  const size_t g = ((size_t)blockIdx.x * 256 + threadIdx.x) * 8;
  float4 a = *(const float4*)(values + g);
  float4 b = *(const float4*)(values + g + 4);
  uint4 pk;
  pk.x = f2bf(a.x) | (f2bf(a.y) << 16);
  pk.y = f2bf(a.z) | (f2bf(a.w) << 16);
  pk.z = f2bf(b.x) | (f2bf(b.y) << 16);
  pk.w = f2bf(b.z) | (f2bf(b.w) << 16);
  *(uint4*)(vbf + g / 2) = pk;
}

// ---------------- gather bf16: wave-per-row, 4 L3 phases ----------------
__global__ __launch_bounds__(256) void gather_bf16(
    const float* __restrict__ wgt, const int* __restrict__ vidx,
    const unsigned short* __restrict__ vbf, float* __restrict__ out) {
  const int t = blockIdx.x;
  const int tid = threadIdx.x, w = tid >> 6, lane = tid & 63;
  __shared__ float ws_[256];
  __shared__ int vs_[256];
  __shared__ float part[4 * 520];
  ws_[tid] = wgt[(size_t)t * 256 + tid];
  vs_[tid] = vidx[(size_t)t * 256 + tid];
  __syncthreads();
  float acc[8] = {};
  const int c0 = lane * 8;
  #pragma unroll 1
  for (int phase = 0; phase < 4; ++phase) {
    for (int e = w; e < 256; e += 4) {
      const int row = vs_[e];                 // wave-uniform scalar
      if ((row >> 14) != phase) continue;     // uniform branch, no divergence
      const float wv = ws_[e];
      uint4 pk = *(const uint4*)(vbf + (size_t)row * CDIM + c0);
      acc[0] += wv * bf2f(pk.x & 0xffff); acc[1] += wv * bf2f(pk.x >> 16);
      acc[2] += wv * bf2f(pk.y & 0xffff); acc[3] += wv * bf2f(pk.y >> 16);
      acc[4] += wv * bf2f(pk.z & 0xffff); acc[5] += wv * bf2f(pk.z >> 16);
      acc[6] += wv * bf2f(pk.w & 0xffff); acc[7] += wv * bf2f(pk.w >> 16);
    }
  }
  #pragma unroll
  for (int j = 0; j < 8; j += 4)
    *(float4*)&part[w * 520 + c0 + j] =
        make_float4(acc[j], acc[j + 1], acc[j + 2], acc[j + 3]);
  __syncthreads();
  const int c2 = tid * 2;
  float r0 = part[c2] + part[520 + c2] + part[1040 + c2] + part[1560 + c2];
  float r1 = part[c2 + 1] + part[520 + c2 + 1] + part[1040 + c2 + 1] + part[1560 + c2 + 1];
  *(float2*)(out + (size_t)t * CDIM + c2) = make_float2(r0, r1);
}

// ---------------- fallback fp32 gather (round-4, for small ws) ----------------
__global__ __launch_bounds__(256) void gather_kernel(
    const float* __restrict__ wgt, const int* __restrict__ vidx,
    const float* __restrict__ values, float* __restrict__ out) {
  const int tp = blockIdx.x;
  const int tid = threadIdx.x;
  __shared__ float ws_[512];
  __shared__ int vs_[512];
  ws_[tid] = wgt[(size_t)tp * 512 + tid];
  ws_[tid + 256] = wgt[(size_t)tp * 512 + tid + 256];
  vs_[tid] = vidx[(size_t)tp * 512 + tid];
  vs_[tid + 256] = vidx[(size_t)tp * 512 + tid + 256];
  __syncthreads();
  const int sub = tid >> 7;
  const int c4 = (tid & 127) * 4;
  const float* wp = &ws_[sub * 256];
  const int* vp = &vs_[sub * 256];
  float4 a = make_float4(0.f, 0.f, 0.f, 0.f);
  #pragma unroll 4
  for (int e = 0; e < 256; ++e) {
    float4 vv = *(const float4*)(values + (size_t)vp[e] * CDIM + c4);
    float wv = wp[e];
    a.x += wv * vv.x; a.y += wv * vv.y; a.z += wv * vv.z; a.w += wv * vv.w;
  }
  *(float4*)(out + (size_t)(tp * 2 + sub) * CDIM + c4) = a;
}

extern "C" void kernel_launch(void* const* d_in, const int* in_sizes, int n_in,
                              void* d_out, int out_size, void* d_ws, size_t ws_size,
                              hipStream_t stream) {
  const float* X      = (const float*)d_in[0];
  const float* W      = (const float*)d_in[1];
  const float* keys   = (const float*)d_in[2];
  const float* values = (const float*)d_in[3];
  const float* gamma  = (const float*)d_in[4];
  const float* beta   = (const float*)d_in[5];
  char* ws = (char*)d_ws;
  float* s1s = (float*)(ws);                  // 0..4 MB
  int*   s1i = (int*)  (ws + (4u << 20));     // 4..8 MB
  float* wgt = (float*)(ws + (8u << 20));     // 8..10 MB
  int*   vix = (int*)  (ws + (10u << 20));    // 10..12 MB
  float* Q   = (float*)(ws + (12u << 20));    // 12..28 MB (dead after dots_sel)
  unsigned int* vbf = (unsigned int*)(ws + (12u << 20));  // 12..76 MB (overlaps dead Q)

  const bool bf16_path = ws_size >= (76u << 20);

  qgemm_ln<<<dim3(32, 16), 256, 0, stream>>>(X, W, gamma, beta, Q);
  dots_sel<<<dim3(16, 64), 512, 0, stream>>>(Q, keys, s1s, s1i);
  stage2_kernel<<<4096, 256, 0, stream>>>(s1s, s1i, wgt, vix);
  if (bf16_path) {
    convert_values<<<16384, 256, 0, stream>>>(values, vbf);  // after dots_sel: Q is dead
    gather_bf16<<<2048, 256, 0, stream>>>(wgt, vix, (const unsigned short*)vbf, (float*)d_out);
  } else {
    gather_kernel<<<1024, 256, 0, stream>>>(wgt, vix, values, (float*)d_out);
  }
}

// Round 2
// 494.233 us; speedup vs baseline: 3.8124x; 3.8124x over previous
//
#include <hip/hip_runtime.h>
#include <math.h>

#define DQ 2048
#define CDIM 512
#define NKEYS 256
#define KSEL 32

__device__ __forceinline__ bool rank_before(float as, int ai, float bs, int bi) {
  return (as > bs) || (as == bs && ai < bi);
}
static __device__ __forceinline__ float bf2f(unsigned int u) {
  union { unsigned int i; float f; } v; v.i = u << 16; return v.f;
}
static __device__ __forceinline__ unsigned int f2bf(float f) {
  union { float f; unsigned int i; } v; v.f = f;
  unsigned int r = v.i + 0x7fffu + ((v.i >> 16) & 1u);
  return r >> 16;
}

// ---------------- q = LN(X * Wq^T) fused (fp32 vector GEMM + groupwise LN) ----------------
__global__ __launch_bounds__(256) void qgemm_ln(
    const float* __restrict__ X, const float* __restrict__ W,
    const float* __restrict__ gamma, const float* __restrict__ beta,
    float* __restrict__ Q) {
  __shared__ float As[16 * 68];   // [k][m]
  __shared__ float Bs[16 * 132];  // [k][n]
  const int tid = threadIdx.x;
  const int m0 = blockIdx.x * 64, n0 = blockIdx.y * 128;
  const int tx = tid & 15, ty = tid >> 4;
  const int am = tid >> 2, ak = (tid & 3) * 4;
  const int bn = tid >> 1, bk = (tid & 1) * 8;
  float acc[4][8] = {};
  // software prefetch of first tile
  float4 av  = *(const float4*)&X[(size_t)(m0 + am) * CDIM + ak];
  float4 bv0 = *(const float4*)&W[(size_t)(n0 + bn) * CDIM + bk];
  float4 bv1 = *(const float4*)&W[(size_t)(n0 + bn) * CDIM + bk + 4];
  for (int kt = 0; kt < CDIM; kt += 16) {
    __syncthreads();
    As[(ak + 0) * 68 + am] = av.x; As[(ak + 1) * 68 + am] = av.y;
    As[(ak + 2) * 68 + am] = av.z; As[(ak + 3) * 68 + am] = av.w;
    Bs[(bk + 0) * 132 + bn] = bv0.x; Bs[(bk + 1) * 132 + bn] = bv0.y;
    Bs[(bk + 2) * 132 + bn] = bv0.z; Bs[(bk + 3) * 132 + bn] = bv0.w;
    Bs[(bk + 4) * 132 + bn] = bv1.x; Bs[(bk + 5) * 132 + bn] = bv1.y;
    Bs[(bk + 6) * 132 + bn] = bv1.z; Bs[(bk + 7) * 132 + bn] = bv1.w;
    __syncthreads();
    if (kt + 16 < CDIM) {  // prefetch next tile; latency hides behind compute
      av  = *(const float4*)&X[(size_t)(m0 + am) * CDIM + kt + 16 + ak];
      bv0 = *(const float4*)&W[(size_t)(n0 + bn) * CDIM + kt + 16 + bk];
      bv1 = *(const float4*)&W[(size_t)(n0 + bn) * CDIM + kt + 16 + bk + 4];
    }
    #pragma unroll
    for (int kk = 0; kk < 16; ++kk) {
      float4 a4  = *(const float4*)&As[kk * 68 + ty * 4];
      float4 b4a = *(const float4*)&Bs[kk * 132 + tx * 8];
      float4 b4b = *(const float4*)&Bs[kk * 132 + tx * 8 + 4];
      const float ar[4] = {a4.x, a4.y, a4.z, a4.w};
      const float br[8] = {b4a.x, b4a.y, b4a.z, b4a.w, b4b.x, b4b.y, b4b.z, b4b.w};
      #pragma unroll
      for (int i = 0; i < 4; ++i)
        #pragma unroll
        for (int j = 0; j < 8; ++j)
          acc[i][j] += ar[i] * br[j];
    }
  }
  float g[8], bta[8];
  #pragma unroll
  for (int j = 0; j < 8; ++j) { g[j] = gamma[tx * 8 + j]; bta[j] = beta[tx * 8 + j]; }
  #pragma unroll
  for (int i = 0; i < 4; ++i) {
    float s = 0.f, sq = 0.f;
    #pragma unroll
    for (int j = 0; j < 8; ++j) { s += acc[i][j]; sq += acc[i][j] * acc[i][j]; }
    #pragma unroll
    for (int m = 1; m < 16; m <<= 1) {
      s += __shfl_xor(s, m, 64);
      sq += __shfl_xor(sq, m, 64);
    }
    float mean = s * (1.0f / 128.0f);
    float var = sq * (1.0f / 128.0f) - mean * mean;
    float rs = 1.0f / sqrtf(var + 1e-5f);
    float o[8];
    #pragma unroll
    for (int j = 0; j < 8; ++j) o[j] = (acc[i][j] - mean) * rs * g[j] + bta[j];
    float* dst = &Q[(size_t)(m0 + ty * 4 + i) * DQ + n0 + tx * 8];
    *(float4*)dst = make_float4(o[0], o[1], o[2], o[3]);
    *(float4*)(dst + 4) = make_float4(o[4], o[5], o[6], o[7]);
  }
}

// ---------------- dots (tiled fp32 GEMM) + wave-parallel blocked bitonic top-32 ----------------
// Blocked layout: after the GEMM, the 32x256 dot matrix is transposed through
// LDS (chunk-XOR swizzled) so each token's 256 scores live on 16 lanes x 16
// contiguous elements; all 4 tokens of a wave sort concurrently in ONE generic
// bitonic-256 (10 of 36 passes cross-lane vs 21 x 4 serially before).
// launch_bounds min-waves 6->4: the 6-wave bound capped regalloc at ~80 VGPRs,
// which demoted s[16]/id[16] to scratch (round-1: 7 GB HBM traffic, 12x slower).
// 4 waves/EU allows 128 VGPRs; sort state (~100 VGPRs) stays in registers.
__global__ __launch_bounds__(512, 4) void dots_sel(
    const float* __restrict__ Q, const float* __restrict__ keys,
    float* __restrict__ s1s, int* __restrict__ s1i) {
  const int hp = blockIdx.x;
  const int chunk = blockIdx.y;
  const int h = hp >> 1, p = hp & 1;
  const int t0 = chunk * 32;
  // Qs (32*132) + Bs (16*260) = 33536 B, aliased with Sd (32*264 = 33792 B)
  __shared__ __align__(16) float smem[32 * 264];
  float* Qs = smem;            // during GEMM
  float* Bs = smem + 32 * 132; // during GEMM
  float* Sd = smem;            // after GEMM (Qs/Bs dead)
  const int tid = threadIdx.x;
  const int w = tid >> 6, lane = tid & 63;
  {
    const int tok = tid >> 4, d0 = (tid & 15) * 8;
    const float* src = &Q[(size_t)(t0 + tok) * DQ + p * 1024 + h * 128 + d0];
    *(float4*)&Qs[tok * 132 + d0] = *(const float4*)src;
    *(float4*)&Qs[tok * 132 + d0 + 4] = *(const float4*)(src + 4);
  }
  const int bn = tid >> 1, bkh = (tid & 1) * 8;
  const float* kbase = keys + ((size_t)(h * NKEYS + bn) * 2 + p) * 128;
  float acc[4][4] = {};
  float4 b0 = *(const float4*)&kbase[bkh];
  float4 b1 = *(const float4*)&kbase[bkh + 4];
  for (int kt = 0; kt < 128; kt += 16) {
    __syncthreads();
    Bs[(bkh + 0) * 260 + bn] = b0.x; Bs[(bkh + 1) * 260 + bn] = b0.y;
    Bs[(bkh + 2) * 260 + bn] = b0.z; Bs[(bkh + 3) * 260 + bn] = b0.w;
    Bs[(bkh + 4) * 260 + bn] = b1.x; Bs[(bkh + 5) * 260 + bn] = b1.y;
    Bs[(bkh + 6) * 260 + bn] = b1.z; Bs[(bkh + 7) * 260 + bn] = b1.w;
    __syncthreads();
    if (kt + 16 < 128) {  // prefetch next key K-slab
      b0 = *(const float4*)&kbase[kt + 16 + bkh];
      b1 = *(const float4*)&kbase[kt + 16 + bkh + 4];
    }
    #pragma unroll
    for (int k4 = 0; k4 < 16; k4 += 4) {
      float4 a0 = *(const float4*)&Qs[(w * 4 + 0) * 132 + kt + k4];
      float4 a1 = *(const float4*)&Qs[(w * 4 + 1) * 132 + kt + k4];
      float4 a2 = *(const float4*)&Qs[(w * 4 + 2) * 132 + kt + k4];
      float4 a3 = *(const float4*)&Qs[(w * 4 + 3) * 132 + kt + k4];
      const float a0r[4] = {a0.x, a0.y, a0.z, a0.w};
      const float a1r[4] = {a1.x, a1.y, a1.z, a1.w};
      const float a2r[4] = {a2.x, a2.y, a2.z, a2.w};
      const float a3r[4] = {a3.x, a3.y, a3.z, a3.w};
      #pragma unroll
      for (int kk = 0; kk < 4; ++kk) {
        float4 b4 = *(const float4*)&Bs[(k4 + kk) * 260 + lane * 4];
        const float br[4] = {b4.x, b4.y, b4.z, b4.w};
        #pragma unroll
        for (int j = 0; j < 4; ++j) {
          acc[0][j] += a0r[kk] * br[j];
          acc[1][j] += a1r[kk] * br[j];
          acc[2][j] += a2r[kk] * br[j];
          acc[3][j] += a3r[kk] * br[j];
        }
      }
    }
  }
  // ---- transpose dots into Sd: token rows of 264 floats, 16B chunks XOR-swizzled
  // by (token&3). Row stride 264 words == 8 mod 32 -> both write (fixed i: full
  // chunk permutation of one row, contiguous 1KB) and read (analysis: all 8
  // bank-quads covered evenly) sit at the 8-words/bank ds_*_b128 floor.
  __syncthreads();  // all waves done reading Qs/Bs before overwrite
  #pragma unroll
  for (int i = 0; i < 4; ++i)
    *(float4*)&Sd[(w * 4 + i) * 264 + ((lane ^ i) << 2)] =
        make_float4(acc[i][0], acc[i][1], acc[i][2], acc[i][3]);
  __syncthreads();

  // ---- blocked re-read: lane group of 16 per token, 16 contiguous scores/lane
  const int i4 = lane >> 4;       // token sub-index within wave (== token&3)
  const int gl = lane & 15;       // lane within token group
  const int tokl = w * 4 + i4;    // local token row
  float s[16]; int id[16];
  #pragma unroll
  for (int j = 0; j < 4; ++j) {
    const int pc = ((gl << 2) + j) ^ i4;  // physical chunk (undo swizzle)
    const float4 v = *(const float4*)&Sd[tokl * 264 + (pc << 2)];
    s[4 * j + 0] = v.x; s[4 * j + 1] = v.y;
    s[4 * j + 2] = v.z; s[4 * j + 3] = v.w;
    id[4 * j + 0] = (gl << 4) + 4 * j + 0;
    id[4 * j + 1] = (gl << 4) + 4 * j + 1;
    id[4 * j + 2] = (gl << 4) + 4 * j + 2;
    id[4 * j + 3] = (gl << 4) + 4 * j + 3;
  }

  // ---- generic bitonic-256, descending, tie -> lower id. Element e = gl*16+r.
  // dir(e) at level K: (e & K) != 0 -> ascending pair order (matches prior code).
  #define CEL(A, B, DD)                                                        \
    {                                                                          \
      bool sw_ = (DD) ? rank_before(s[A], id[A], s[B], id[B])                  \
                      : rank_before(s[B], id[B], s[A], id[A]);                 \
      if (sw_) {                                                               \
        float tf_ = s[A]; s[A] = s[B]; s[B] = tf_;                             \
        int ti_ = id[A]; id[A] = id[B]; id[B] = ti_;                           \
      }                                                                        \
    }
  // in-register pass: partner r^L within the lane (L < 16)
  #define PASS_R(KK, LL)                                                       \
    _Pragma("unroll")                                                          \
    for (int r_ = 0; r_ < 16; ++r_)                                            \
      if (!(r_ & (LL))) {                                                      \
        const bool dd_ = ((((gl << 4) + r_) & (KK)) != 0);                     \
        CEL(r_, r_ | (LL), dd_);                                               \
      }
  // cross-lane pass: partner lane gl ^ (L/16), same r (L >= 16); xor mask < 16
  // so shuffles never leave the 16-lane token group.
  #define PASS_X(KK, LL)                                                       \
    {                                                                          \
      const bool dd_x = ((gl & ((KK) >> 4)) != 0);                             \
      const bool amHigh_ = ((gl & ((LL) >> 4)) != 0);                          \
      const bool flip_ = amHigh_ != dd_x;                                      \
      _Pragma("unroll")                                                        \
      for (int r_ = 0; r_ < 16; ++r_) {                                        \
        float os_ = __shfl_xor(s[r_], (LL) >> 4, 64);                          \
        int oi_ = __shfl_xor(id[r_], (LL) >> 4, 64);                           \
        bool take_ = rank_before(os_, oi_, s[r_], id[r_]) != flip_;            \
        if (take_) { s[r_] = os_; id[r_] = oi_; }                              \
      }                                                                        \
    }

  PASS_R(2, 1);
  PASS_R(4, 2); PASS_R(4, 1);
  PASS_R(8, 4); PASS_R(8, 2); PASS_R(8, 1);
  PASS_R(16, 8); PASS_R(16, 4); PASS_R(16, 2); PASS_R(16, 1);
  PASS_X(32, 16);
  PASS_R(32, 8); PASS_R(32, 4); PASS_R(32, 2); PASS_R(32, 1);
  PASS_X(64, 32); PASS_X(64, 16);
  PASS_R(64, 8); PASS_R(64, 4); PASS_R(64, 2); PASS_R(64, 1);
  PASS_X(128, 64); PASS_X(128, 32); PASS_X(128, 16);
  PASS_R(128, 8); PASS_R(128, 4); PASS_R(128, 2); PASS_R(128, 1);
  PASS_X(256, 128); PASS_X(256, 64); PASS_X(256, 32); PASS_X(256, 16);
  PASS_R(256, 8); PASS_R(256, 4); PASS_R(256, 2); PASS_R(256, 1);

  #undef CEL
  #undef PASS_R
  #undef PASS_X

  // top-32 = sorted positions 0..31 = lanes gl 0,1 (16 regs each)
  if (gl < 2) {
    const int inst = (t0 + tokl) * 16 + hp;
    #pragma unroll
    for (int j = 0; j < 4; ++j) {
      *(float4*)&s1s[(size_t)inst * KSEL + (gl << 4) + 4 * j] =
          make_float4(s[4 * j], s[4 * j + 1], s[4 * j + 2], s[4 * j + 3]);
      *(int4*)&s1i[(size_t)inst * KSEL + (gl << 4) + 4 * j] =
          make_int4(id[4 * j], id[4 * j + 1], id[4 * j + 2], id[4 * j + 3]);
    }
  }
}

// ---------------- stage-2: pruned 119-candidate bitonic top-32 + softmax ----------------
__constant__ unsigned short slot_ij[128] = {
  0,1,2,3,4,5,6,7,8,9,10,11,12,13,14,15,16,17,18,19,20,21,22,23,24,25,26,27,28,29,30,31,
  32,33,34,35,36,37,38,39,40,41,42,43,44,45,46,47,
  64,65,66,67,68,69,70,71,72,73,
  96,97,98,99,100,101,102,103,
  128,129,130,131,132,133,
  160,161,162,163,164,
  192,193,194,195,
  224,225,226,227,
  256,257,258,
  288,289,290,
  320,321, 352,353, 384,385, 416,417, 448,449, 480,481,
  512,544,576,608,640,672,704,736,768,800,832,864,896,928,960,992,
  0xFFFF,0xFFFF,0xFFFF,0xFFFF,0xFFFF,0xFFFF,0xFFFF,0xFFFF,0xFFFF
};

__global__ __launch_bounds__(256) void stage2_kernel(
    const float* __restrict__ s1s, const int* __restrict__ s1i,
    float* __restrict__ wgt, int* __restrict__ vidx) {
  const int th = blockIdx.x * 4 + (threadIdx.x >> 6);
  const int lane = threadIdx.x & 63;
  const int bx = th * 64;
  const int by = bx + 32;
  float s[2]; int id[2];
  #pragma unroll
  for (int r = 0; r < 2; ++r) {
    int sl = slot_ij[lane * 2 + r];
    if (sl != 0xFFFF) {
      s[r] = s1s[bx + (sl >> 5)] + s1s[by + (sl & 31)];
      id[r] = sl;
    } else {
      s[r] = -INFINITY; id[r] = 0x7fffffff;
    }
  }
  #define CE2(dd)                                                              \
    {                                                                          \
      bool sw = (dd) ? rank_before(s[0], id[0], s[1], id[1])                   \
                     : rank_before(s[1], id[1], s[0], id[0]);                  \
      if (sw) {                                                                \
        float ts = s[0]; s[0] = s[1]; s[1] = ts;                               \
        int ti = id[0]; id[0] = id[1]; id[1] = ti;                             \
      }                                                                        \
    }
  #define CROSS2(L, dd)                                                        \
    {                                                                          \
      bool amHigh = (lane & (L)) != 0;                                         \
      bool flip = amHigh != (dd);                                              \
      _Pragma("unroll")                                                        \
      for (int r = 0; r < 2; ++r) {                                            \
        float os = __shfl_xor(s[r], (L), 64);                                  \
        int oi = __shfl_xor(id[r], (L), 64);                                   \
        bool take = rank_before(os, oi, s[r], id[r]) != flip;                  \
        if (take) { s[r] = os; id[r] = oi; }                                   \
      }                                                                        \
    }
  { bool dd = (lane & 1) != 0; CE2(dd); }
  #pragma unroll
  for (int K = 4; K <= 128; K <<= 1) {
    bool dd = (lane & (K >> 1)) != 0;
    #pragma unroll
    for (int L = K >> 2; L >= 1; L >>= 1) CROSS2(L, dd);
    CE2(dd);
  }
  #undef CE2
  #undef CROSS2
  float smax = __shfl(s[0], 0, 64);
  float e0 = 0.f, e1 = 0.f;
  if (lane < 16) { e0 = expf(s[0] - smax); e1 = expf(s[1] - smax); }
  float part = e0 + e1;
  #pragma unroll
  for (int m = 1; m < 16; m <<= 1) part += __shfl_xor(part, m, 64);
  if (lane < 16) {
    int f0 = id[0], f1 = id[1];
    int vi0 = s1i[bx + (f0 >> 5)] * NKEYS + s1i[by + (f0 & 31)];
    int vi1 = s1i[bx + (f1 >> 5)] * NKEYS + s1i[by + (f1 & 31)];
    wgt[(size_t)th * KSEL + lane * 2] = e0 / part;
    wgt[(size_t)th * KSEL + lane * 2 + 1] = e1 / part;
    vidx[(size_t)th * KSEL + lane * 2] = vi0;
    vidx[(size_t)th * KSEL + lane * 2 + 1] = vi1;
  }
}

// ---------------- values fp32 -> bf16 (RNE) one-pass convert ----------------
__global__ __launch_bounds__(256) void convert_values(
    const float* __restrict__ values, unsigned int* __restrict__ vbf) {
  const size_t g = ((size_t)blockIdx.x * 256 + threadIdx.x) * 8;
  float4 a = *(const float4*)(values + g);
  float4 b = *(const float4*)(values + g + 4);
  uint4 pk;
  pk.x = f2bf(a.x) | (f2bf(a.y) << 16);
  pk.y = f2bf(a.z) | (f2bf(a.w) << 16);
  pk.z = f2bf(b.x) | (f2bf(b.y) << 16);
  pk.w = f2bf(b.z) | (f2bf(b.w) << 16);
  *(uint4*)(vbf + g / 2) = pk;
}

// ---------------- gather bf16: wave-per-row, 4 L3 phases ----------------
__global__ __launch_bounds__(256) void gather_bf16(
    const float* __restrict__ wgt, const int* __restrict__ vidx,
    const unsigned short* __restrict__ vbf, float* __restrict__ out) {
  const int t = blockIdx.x;
  const int tid = threadIdx.x, w = tid >> 6, lane = tid & 63;
  __shared__ float ws_[256];
  __shared__ int vs_[256];
  __shared__ float part[4 * 520];
  ws_[tid] = wgt[(size_t)t * 256 + tid];
  vs_[tid] = vidx[(size_t)t * 256 + tid];
  __syncthreads();
  float acc[8] = {};
  const int c0 = lane * 8;
  #pragma unroll 1
  for (int phase = 0; phase < 4; ++phase) {
    for (int e = w; e < 256; e += 4) {
      const int row = vs_[e];                 // wave-uniform scalar
      if ((row >> 14) != phase) continue;     // uniform branch, no divergence
      const float wv = ws_[e];
      uint4 pk = *(const uint4*)(vbf + (size_t)row * CDIM + c0);
      acc[0] += wv * bf2f(pk.x & 0xffff); acc[1] += wv * bf2f(pk.x >> 16);
      acc[2] += wv * bf2f(pk.y & 0xffff); acc[3] += wv * bf2f(pk.y >> 16);
      acc[4] += wv * bf2f(pk.z & 0xffff); acc[5] += wv * bf2f(pk.z >> 16);
      acc[6] += wv * bf2f(pk.w & 0xffff); acc[7] += wv * bf2f(pk.w >> 16);
    }
  }
  #pragma unroll
  for (int j = 0; j < 8; j += 4)
    *(float4*)&part[w * 520 + c0 + j] =
        make_float4(acc[j], acc[j + 1], acc[j + 2], acc[j + 3]);
  __syncthreads();
  const int c2 = tid * 2;
  float r0 = part[c2] + part[520 + c2] + part[1040 + c2] + part[1560 + c2];
  float r1 = part[c2 + 1] + part[520 + c2 + 1] + part[1040 + c2 + 1] + part[1560 + c2 + 1];
  *(float2*)(out + (size_t)t * CDIM + c2) = make_float2(r0, r1);
}

// ---------------- fallback fp32 gather (round-4, for small ws) ----------------
__global__ __launch_bounds__(256) void gather_kernel(
    const float* __restrict__ wgt, const int* __restrict__ vidx,
    const float* __restrict__ values, float* __restrict__ out) {
  const int tp = blockIdx.x;
  const int tid = threadIdx.x;
  __shared__ float ws_[512];
  __shared__ int vs_[512];
  ws_[tid] = wgt[(size_t)tp * 512 + tid];
  ws_[tid + 256] = wgt[(size_t)tp * 512 + tid + 256];
  vs_[tid] = vidx[(size_t)tp * 512 + tid];
  vs_[tid + 256] = vidx[(size_t)tp * 512 + tid + 256];
  __syncthreads();
  const int sub = tid >> 7;
  const int c4 = (tid & 127) * 4;
  const float* wp = &ws_[sub * 256];
  const int* vp = &vs_[sub * 256];
  float4 a = make_float4(0.f, 0.f, 0.f, 0.f);
  #pragma unroll 4
  for (int e = 0; e < 256; ++e) {
    float4 vv = *(const float4*)(values + (size_t)vp[e] * CDIM + c4);
    float wv = wp[e];
    a.x += wv * vv.x; a.y += wv * vv.y; a.z += wv * vv.z; a.w += wv * vv.w;
  }
  *(float4*)(out + (size_t)(tp * 2 + sub) * CDIM + c4) = a;
}

extern "C" void kernel_launch(void* const* d_in, const int* in_sizes, int n_in,
                              void* d_out, int out_size, void* d_ws, size_t ws_size,
                              hipStream_t stream) {
  const float* X      = (const float*)d_in[0];
  const float* W      = (const float*)d_in[1];
  const float* keys   = (const float*)d_in[2];
  const float* values = (const float*)d_in[3];
  const float* gamma  = (const float*)d_in[4];
  const float* beta   = (const float*)d_in[5];
  char* ws = (char*)d_ws;
  float* s1s = (float*)(ws);                  // 0..4 MB
  int*   s1i = (int*)  (ws + (4u << 20));     // 4..8 MB
  float* wgt = (float*)(ws + (8u << 20));     // 8..10 MB
  int*   vix = (int*)  (ws + (10u << 20));    // 10..12 MB
  float* Q   = (float*)(ws + (12u << 20));    // 12..28 MB (dead after dots_sel)
  unsigned int* vbf = (unsigned int*)(ws + (12u << 20));  // 12..76 MB (overlaps dead Q)

  const bool bf16_path = ws_size >= (76u << 20);

  qgemm_ln<<<dim3(32, 16), 256, 0, stream>>>(X, W, gamma, beta, Q);
  dots_sel<<<dim3(16, 64), 512, 0, stream>>>(Q, keys, s1s, s1i);
  stage2_kernel<<<4096, 256, 0, stream>>>(s1s, s1i, wgt, vix);
  if (bf16_path) {
    convert_values<<<16384, 256, 0, stream>>>(values, vbf);  // after dots_sel: Q is dead
    gather_bf16<<<2048, 256, 0, stream>>>(wgt, vix, (const unsigned short*)vbf, (float*)d_out);
  } else {
    gather_kernel<<<1024, 256, 0, stream>>>(wgt, vix, values, (float*)d_out);
  }
}

// Round 3
// 454.949 us; speedup vs baseline: 4.1416x; 1.0863x over previous
//
#include <hip/hip_runtime.h>
#include <math.h>

#define DQ 2048
#define CDIM 512
#define NKEYS 256
#define KSEL 32

__device__ __forceinline__ bool rank_before(float as, int ai, float bs, int bi) {
  return (as > bs) || (as == bs && ai < bi);
}
static __device__ __forceinline__ float bf2f(unsigned int u) {
  union { unsigned int i; float f; } v; v.i = u << 16; return v.f;
}
static __device__ __forceinline__ unsigned int f2bf(float f) {
  union { float f; unsigned int i; } v; v.f = f;
  unsigned int r = v.i + 0x7fffu + ((v.i >> 16) & 1u);
  return r >> 16;
}

// ---------------- q = LN(X * Wq^T) fused (fp32 vector GEMM + groupwise LN) ----------------
__global__ __launch_bounds__(256) void qgemm_ln(
    const float* __restrict__ X, const float* __restrict__ W,
    const float* __restrict__ gamma, const float* __restrict__ beta,
    float* __restrict__ Q) {
  __shared__ float As[16 * 68];   // [k][m]
  __shared__ float Bs[16 * 132];  // [k][n]
  const int tid = threadIdx.x;
  const int m0 = blockIdx.x * 64, n0 = blockIdx.y * 128;
  const int tx = tid & 15, ty = tid >> 4;
  const int am = tid >> 2, ak = (tid & 3) * 4;
  const int bn = tid >> 1, bk = (tid & 1) * 8;
  float acc[4][8] = {};
  // software prefetch of first tile
  float4 av  = *(const float4*)&X[(size_t)(m0 + am) * CDIM + ak];
  float4 bv0 = *(const float4*)&W[(size_t)(n0 + bn) * CDIM + bk];
  float4 bv1 = *(const float4*)&W[(size_t)(n0 + bn) * CDIM + bk + 4];
  for (int kt = 0; kt < CDIM; kt += 16) {
    __syncthreads();
    As[(ak + 0) * 68 + am] = av.x; As[(ak + 1) * 68 + am] = av.y;
    As[(ak + 2) * 68 + am] = av.z; As[(ak + 3) * 68 + am] = av.w;
    Bs[(bk + 0) * 132 + bn] = bv0.x; Bs[(bk + 1) * 132 + bn] = bv0.y;
    Bs[(bk + 2) * 132 + bn] = bv0.z; Bs[(bk + 3) * 132 + bn] = bv0.w;
    Bs[(bk + 4) * 132 + bn] = bv1.x; Bs[(bk + 5) * 132 + bn] = bv1.y;
    Bs[(bk + 6) * 132 + bn] = bv1.z; Bs[(bk + 7) * 132 + bn] = bv1.w;
    __syncthreads();
    if (kt + 16 < CDIM) {  // prefetch next tile; latency hides behind compute
      av  = *(const float4*)&X[(size_t)(m0 + am) * CDIM + kt + 16 + ak];
      bv0 = *(const float4*)&W[(size_t)(n0 + bn) * CDIM + kt + 16 + bk];
      bv1 = *(const float4*)&W[(size_t)(n0 + bn) * CDIM + kt + 16 + bk + 4];
    }
    #pragma unroll
    for (int kk = 0; kk < 16; ++kk) {
      float4 a4  = *(const float4*)&As[kk * 68 + ty * 4];
      float4 b4a = *(const float4*)&Bs[kk * 132 + tx * 8];
      float4 b4b = *(const float4*)&Bs[kk * 132 + tx * 8 + 4];
      const float ar[4] = {a4.x, a4.y, a4.z, a4.w};
      const float br[8] = {b4a.x, b4a.y, b4a.z, b4a.w, b4b.x, b4b.y, b4b.z, b4b.w};
      #pragma unroll
      for (int i = 0; i < 4; ++i)
        #pragma unroll
        for (int j = 0; j < 8; ++j)
          acc[i][j] += ar[i] * br[j];
    }
  }
  float g[8], bta[8];
  #pragma unroll
  for (int j = 0; j < 8; ++j) { g[j] = gamma[tx * 8 + j]; bta[j] = beta[tx * 8 + j]; }
  #pragma unroll
  for (int i = 0; i < 4; ++i) {
    float s = 0.f, sq = 0.f;
    #pragma unroll
    for (int j = 0; j < 8; ++j) { s += acc[i][j]; sq += acc[i][j] * acc[i][j]; }
    #pragma unroll
    for (int m = 1; m < 16; m <<= 1) {
      s += __shfl_xor(s, m, 64);
      sq += __shfl_xor(sq, m, 64);
    }
    float mean = s * (1.0f / 128.0f);
    float var = sq * (1.0f / 128.0f) - mean * mean;
    float rs = 1.0f / sqrtf(var + 1e-5f);
    float o[8];
    #pragma unroll
    for (int j = 0; j < 8; ++j) o[j] = (acc[i][j] - mean) * rs * g[j] + bta[j];
    float* dst = &Q[(size_t)(m0 + ty * 4 + i) * DQ + n0 + tx * 8];
    *(float4*)dst = make_float4(o[0], o[1], o[2], o[3]);
    *(float4*)(dst + 4) = make_float4(o[4], o[5], o[6], o[7]);
  }
}

// ---------------- dots (tiled fp32 GEMM) + in-register bitonic top-32 ----------------
// Sort structure = proven round-0 network (128 us). Single change this round:
// the 4 independent token sorts run as 2 PAIRS, each pair's two sorts
// interleaved at pass granularity (sA/iA + sB/iB register state). The serial
// ds_bpermute chain per wave drops 144 -> 72 passes; shuffles of the two sorts
// pipeline in the LDS queue. Blocked-layout variant (rounds 1-2) REGRESSED
// (166 us, VALU-throughput-bound) - do not revisit.
// launch_bounds (512,5): VGPR cap ~102 for ~56-72 demand. (512,6) capped at 80
// and round-1 showed the demotion failure mode; occupancy is LDS-capped at
// 4 blocks/CU either way so the weaker promise costs nothing.
__global__ __launch_bounds__(512, 5) void dots_sel(
    const float* __restrict__ Q, const float* __restrict__ keys,
    float* __restrict__ s1s, int* __restrict__ s1i) {
  const int hp = blockIdx.x;
  const int chunk = blockIdx.y;
  const int h = hp >> 1, p = hp & 1;
  const int t0 = chunk * 32;
  __shared__ float Qs[32 * 132];
  __shared__ float Bs[16 * 260];
  const int tid = threadIdx.x;
  const int w = tid >> 6, lane = tid & 63;
  {
    const int tok = tid >> 4, d0 = (tid & 15) * 8;
    const float* src = &Q[(size_t)(t0 + tok) * DQ + p * 1024 + h * 128 + d0];
    *(float4*)&Qs[tok * 132 + d0] = *(const float4*)src;
    *(float4*)&Qs[tok * 132 + d0 + 4] = *(const float4*)(src + 4);
  }
  const int bn = tid >> 1, bkh = (tid & 1) * 8;
  const float* kbase = keys + ((size_t)(h * NKEYS + bn) * 2 + p) * 128;
  float acc[4][4] = {};
  float4 b0 = *(const float4*)&kbase[bkh];
  float4 b1 = *(const float4*)&kbase[bkh + 4];
  for (int kt = 0; kt < 128; kt += 16) {
    __syncthreads();
    Bs[(bkh + 0) * 260 + bn] = b0.x; Bs[(bkh + 1) * 260 + bn] = b0.y;
    Bs[(bkh + 2) * 260 + bn] = b0.z; Bs[(bkh + 3) * 260 + bn] = b0.w;
    Bs[(bkh + 4) * 260 + bn] = b1.x; Bs[(bkh + 5) * 260 + bn] = b1.y;
    Bs[(bkh + 6) * 260 + bn] = b1.z; Bs[(bkh + 7) * 260 + bn] = b1.w;
    __syncthreads();
    if (kt + 16 < 128) {  // prefetch next key K-slab
      b0 = *(const float4*)&kbase[kt + 16 + bkh];
      b1 = *(const float4*)&kbase[kt + 16 + bkh + 4];
    }
    #pragma unroll
    for (int k4 = 0; k4 < 16; k4 += 4) {
      float4 a0 = *(const float4*)&Qs[(w * 4 + 0) * 132 + kt + k4];
      float4 a1 = *(const float4*)&Qs[(w * 4 + 1) * 132 + kt + k4];
      float4 a2 = *(const float4*)&Qs[(w * 4 + 2) * 132 + kt + k4];
      float4 a3 = *(const float4*)&Qs[(w * 4 + 3) * 132 + kt + k4];
      const float a0r[4] = {a0.x, a0.y, a0.z, a0.w};
      const float a1r[4] = {a1.x, a1.y, a1.z, a1.w};
      const float a2r[4] = {a2.x, a2.y, a2.z, a2.w};
      const float a3r[4] = {a3.x, a3.y, a3.z, a3.w};
      #pragma unroll
      for (int kk = 0; kk < 4; ++kk) {
        float4 b4 = *(const float4*)&Bs[(k4 + kk) * 260 + lane * 4];
        const float br[4] = {b4.x, b4.y, b4.z, b4.w};
        #pragma unroll
        for (int j = 0; j < 4; ++j) {
          acc[0][j] += a0r[kk] * br[j];
          acc[1][j] += a1r[kk] * br[j];
          acc[2][j] += a2r[kk] * br[j];
          acc[3][j] += a3r[kk] * br[j];
        }
      }
    }
  }
  // ---- paired in-register bitonic top-32 (2 concurrent sorts per iteration)
  #define CE1(S, I, a, b, dd)                                                  \
    {                                                                          \
      bool sw_ = (dd) ? rank_before(S[a], I[a], S[b], I[b])                    \
                      : rank_before(S[b], I[b], S[a], I[a]);                   \
      if (sw_) {                                                               \
        float ts_ = S[a]; S[a] = S[b]; S[b] = ts_;                             \
        int ti_ = I[a]; I[a] = I[b]; I[b] = ti_;                               \
      }                                                                        \
    }
  #define CEP(a, b, dd) { CE1(sA, iA, a, b, dd) CE1(sB, iB, a, b, dd) }
  #define CROSSP(L, dd)                                                        \
    {                                                                          \
      bool amHigh = (lane & (L)) != 0;                                         \
      bool flip = amHigh != (dd);                                              \
      _Pragma("unroll")                                                        \
      for (int r = 0; r < 4; ++r) {                                            \
        float osA = __shfl_xor(sA[r], (L), 64);                                \
        int oiA = __shfl_xor(iA[r], (L), 64);                                  \
        float osB = __shfl_xor(sB[r], (L), 64);                                \
        int oiB = __shfl_xor(iB[r], (L), 64);                                  \
        bool tA = rank_before(osA, oiA, sA[r], iA[r]) != flip;                 \
        if (tA) { sA[r] = osA; iA[r] = oiA; }                                  \
        bool tB = rank_before(osB, oiB, sB[r], iB[r]) != flip;                 \
        if (tB) { sB[r] = osB; iB[r] = oiB; }                                  \
      }                                                                        \
    }
  #pragma unroll
  for (int ii = 0; ii < 4; ii += 2) {  // fully unrolled: acc indexing stays static
    float sA[4], sB[4]; int iA[4], iB[4];
    #pragma unroll
    for (int r = 0; r < 4; ++r) {
      sA[r] = acc[ii][r];     iA[r] = lane * 4 + r;
      sB[r] = acc[ii + 1][r]; iB[r] = lane * 4 + r;
    }
    CEP(0, 1, false); CEP(2, 3, true);
    {
      bool dd = (lane & 1) != 0;
      CEP(0, 2, dd); CEP(1, 3, dd); CEP(0, 1, dd); CEP(2, 3, dd);
    }
    #pragma unroll
    for (int K = 8; K <= 256; K <<= 1) {
      bool dd = (lane & (K >> 2)) != 0;
      #pragma unroll
      for (int L = K >> 3; L >= 1; L >>= 1) CROSSP(L, dd);
      CEP(0, 2, dd); CEP(1, 3, dd); CEP(0, 1, dd); CEP(2, 3, dd);
    }
    const int instA = (t0 + w * 4 + ii) * 16 + hp;
    const int instB = instA + 16;  // token ii+1
    if (lane < 8) {
      *(float4*)&s1s[(size_t)instA * KSEL + lane * 4] = make_float4(sA[0], sA[1], sA[2], sA[3]);
      *(int4*)&s1i[(size_t)instA * KSEL + lane * 4] = make_int4(iA[0], iA[1], iA[2], iA[3]);
      *(float4*)&s1s[(size_t)instB * KSEL + lane * 4] = make_float4(sB[0], sB[1], sB[2], sB[3]);
      *(int4*)&s1i[(size_t)instB * KSEL + lane * 4] = make_int4(iB[0], iB[1], iB[2], iB[3]);
    }
  }
  #undef CE1
  #undef CEP
  #undef CROSSP
}

// ---------------- stage-2: pruned 119-candidate bitonic top-32 + softmax ----------------
__constant__ unsigned short slot_ij[128] = {
  0,1,2,3,4,5,6,7,8,9,10,11,12,13,14,15,16,17,18,19,20,21,22,23,24,25,26,27,28,29,30,31,
  32,33,34,35,36,37,38,39,40,41,42,43,44,45,46,47,
  64,65,66,67,68,69,70,71,72,73,
  96,97,98,99,100,101,102,103,
  128,129,130,131,132,133,
  160,161,162,163,164,
  192,193,194,195,
  224,225,226,227,
  256,257,258,
  288,289,290,
  320,321, 352,353, 384,385, 416,417, 448,449, 480,481,
  512,544,576,608,640,672,704,736,768,800,832,864,896,928,960,992,
  0xFFFF,0xFFFF,0xFFFF,0xFFFF,0xFFFF,0xFFFF,0xFFFF,0xFFFF,0xFFFF
};

__global__ __launch_bounds__(256) void stage2_kernel(
    const float* __restrict__ s1s, const int* __restrict__ s1i,
    float* __restrict__ wgt, int* __restrict__ vidx) {
  const int th = blockIdx.x * 4 + (threadIdx.x >> 6);
  const int lane = threadIdx.x & 63;
  const int bx = th * 64;
  const int by = bx + 32;
  float s[2]; int id[2];
  #pragma unroll
  for (int r = 0; r < 2; ++r) {
    int sl = slot_ij[lane * 2 + r];
    if (sl != 0xFFFF) {
      s[r] = s1s[bx + (sl >> 5)] + s1s[by + (sl & 31)];
      id[r] = sl;
    } else {
      s[r] = -INFINITY; id[r] = 0x7fffffff;
    }
  }
  #define CE2(dd)                                                              \
    {                                                                          \
      bool sw = (dd) ? rank_before(s[0], id[0], s[1], id[1])                   \
                     : rank_before(s[1], id[1], s[0], id[0]);                  \
      if (sw) {                                                                \
        float ts = s[0]; s[0] = s[1]; s[1] = ts;                               \
        int ti = id[0]; id[0] = id[1]; id[1] = ti;                             \
      }                                                                        \
    }
  #define CROSS2(L, dd)                                                        \
    {                                                                          \
      bool amHigh = (lane & (L)) != 0;                                         \
      bool flip = amHigh != (dd);                                              \
      _Pragma("unroll")                                                        \
      for (int r = 0; r < 2; ++r) {                                            \
        float os = __shfl_xor(s[r], (L), 64);                                  \
        int oi = __shfl_xor(id[r], (L), 64);                                   \
        bool take = rank_before(os, oi, s[r], id[r]) != flip;                  \
        if (take) { s[r] = os; id[r] = oi; }                                   \
      }                                                                        \
    }
  { bool dd = (lane & 1) != 0; CE2(dd); }
  #pragma unroll
  for (int K = 4; K <= 128; K <<= 1) {
    bool dd = (lane & (K >> 1)) != 0;
    #pragma unroll
    for (int L = K >> 2; L >= 1; L >>= 1) CROSS2(L, dd);
    CE2(dd);
  }
  #undef CE2
  #undef CROSS2
  float smax = __shfl(s[0], 0, 64);
  float e0 = 0.f, e1 = 0.f;
  if (lane < 16) { e0 = expf(s[0] - smax); e1 = expf(s[1] - smax); }
  float part = e0 + e1;
  #pragma unroll
  for (int m = 1; m < 16; m <<= 1) part += __shfl_xor(part, m, 64);
  if (lane < 16) {
    int f0 = id[0], f1 = id[1];
    int vi0 = s1i[bx + (f0 >> 5)] * NKEYS + s1i[by + (f0 & 31)];
    int vi1 = s1i[bx + (f1 >> 5)] * NKEYS + s1i[by + (f1 & 31)];
    wgt[(size_t)th * KSEL + lane * 2] = e0 / part;
    wgt[(size_t)th * KSEL + lane * 2 + 1] = e1 / part;
    vidx[(size_t)th * KSEL + lane * 2] = vi0;
    vidx[(size_t)th * KSEL + lane * 2 + 1] = vi1;
  }
}

// ---------------- values fp32 -> bf16 (RNE) one-pass convert ----------------
__global__ __launch_bounds__(256) void convert_values(
    const float* __restrict__ values, unsigned int* __restrict__ vbf) {
  const size_t g = ((size_t)blockIdx.x * 256 + threadIdx.x) * 8;
  float4 a = *(const float4*)(values + g);
  float4 b = *(const float4*)(values + g + 4);
  uint4 pk;
  pk.x = f2bf(a.x) | (f2bf(a.y) << 16);
  pk.y = f2bf(a.z) | (f2bf(a.w) << 16);
  pk.z = f2bf(b.x) | (f2bf(b.y) << 16);
  pk.w = f2bf(b.z) | (f2bf(b.w) << 16);
  *(uint4*)(vbf + g / 2) = pk;
}

// ---------------- gather bf16: wave-per-row, 4 L3 phases ----------------
__global__ __launch_bounds__(256) void gather_bf16(
    const float* __restrict__ wgt, const int* __restrict__ vidx,
    const unsigned short* __restrict__ vbf, float* __restrict__ out) {
  const int t = blockIdx.x;
  const int tid = threadIdx.x, w = tid >> 6, lane = tid & 63;
  __shared__ float ws_[256];
  __shared__ int vs_[256];
  __shared__ float part[4 * 520];
  ws_[tid] = wgt[(size_t)t * 256 + tid];
  vs_[tid] = vidx[(size_t)t * 256 + tid];
  __syncthreads();
  float acc[8] = {};
  const int c0 = lane * 8;
  #pragma unroll 1
  for (int phase = 0; phase < 4; ++phase) {
    for (int e = w; e < 256; e += 4) {
      const int row = vs_[e];                 // wave-uniform scalar
      if ((row >> 14) != phase) continue;     // uniform branch, no divergence
      const float wv = ws_[e];
      uint4 pk = *(const uint4*)(vbf + (size_t)row * CDIM + c0);
      acc[0] += wv * bf2f(pk.x & 0xffff); acc[1] += wv * bf2f(pk.x >> 16);
      acc[2] += wv * bf2f(pk.y & 0xffff); acc[3] += wv * bf2f(pk.y >> 16);
      acc[4] += wv * bf2f(pk.z & 0xffff); acc[5] += wv * bf2f(pk.z >> 16);
      acc[6] += wv * bf2f(pk.w & 0xffff); acc[7] += wv * bf2f(pk.w >> 16);
    }
  }
  #pragma unroll
  for (int j = 0; j < 8; j += 4)
    *(float4*)&part[w * 520 + c0 + j] =
        make_float4(acc[j], acc[j + 1], acc[j + 2], acc[j + 3]);
  __syncthreads();
  const int c2 = tid * 2;
  float r0 = part[c2] + part[520 + c2] + part[1040 + c2] + part[1560 + c2];
  float r1 = part[c2 + 1] + part[520 + c2 + 1] + part[1040 + c2 + 1] + part[1560 + c2 + 1];
  *(float2*)(out + (size_t)t * CDIM + c2) = make_float2(r0, r1);
}

// ---------------- fallback fp32 gather (round-4, for small ws) ----------------
__global__ __launch_bounds__(256) void gather_kernel(
    const float* __restrict__ wgt, const int* __restrict__ vidx,
    const float* __restrict__ values, float* __restrict__ out) {
  const int tp = blockIdx.x;
  const int tid = threadIdx.x;
  __shared__ float ws_[512];
  __shared__ int vs_[512];
  ws_[tid] = wgt[(size_t)tp * 512 + tid];
  ws_[tid + 256] = wgt[(size_t)tp * 512 + tid + 256];
  vs_[tid] = vidx[(size_t)tp * 512 + tid];
  vs_[tid + 256] = vidx[(size_t)tp * 512 + tid + 256];
  __syncthreads();
  const int sub = tid >> 7;
  const int c4 = (tid & 127) * 4;
  const float* wp = &ws_[sub * 256];
  const int* vp = &vs_[sub * 256];
  float4 a = make_float4(0.f, 0.f, 0.f, 0.f);
  #pragma unroll 4
  for (int e = 0; e < 256; ++e) {
    float4 vv = *(const float4*)(values + (size_t)vp[e] * CDIM + c4);
    float wv = wp[e];
    a.x += wv * vv.x; a.y += wv * vv.y; a.z += wv * vv.z; a.w += wv * vv.w;
  }
  *(float4*)(out + (size_t)(tp * 2 + sub) * CDIM + c4) = a;
}

extern "C" void kernel_launch(void* const* d_in, const int* in_sizes, int n_in,
                              void* d_out, int out_size, void* d_ws, size_t ws_size,
                              hipStream_t stream) {
  const float* X      = (const float*)d_in[0];
  const float* W      = (const float*)d_in[1];
  const float* keys   = (const float*)d_in[2];
  const float* values = (const float*)d_in[3];
  const float* gamma  = (const float*)d_in[4];
  const float* beta   = (const float*)d_in[5];
  char* ws = (char*)d_ws;
  float* s1s = (float*)(ws);                  // 0..4 MB
  int*   s1i = (int*)  (ws + (4u << 20));     // 4..8 MB
  float* wgt = (float*)(ws + (8u << 20));     // 8..10 MB
  int*   vix = (int*)  (ws + (10u << 20));    // 10..12 MB
  float* Q   = (float*)(ws + (12u << 20));    // 12..28 MB (dead after dots_sel)
  unsigned int* vbf = (unsigned int*)(ws + (12u << 20));  // 12..76 MB (overlaps dead Q)

  const bool bf16_path = ws_size >= (76u << 20);

  qgemm_ln<<<dim3(32, 16), 256, 0, stream>>>(X, W, gamma, beta, Q);
  dots_sel<<<dim3(16, 64), 512, 0, stream>>>(Q, keys, s1s, s1i);
  stage2_kernel<<<4096, 256, 0, stream>>>(s1s, s1i, wgt, vix);
  if (bf16_path) {
    convert_values<<<16384, 256, 0, stream>>>(values, vbf);  // after dots_sel: Q is dead
    gather_bf16<<<2048, 256, 0, stream>>>(wgt, vix, (const unsigned short*)vbf, (float*)d_out);
  } else {
    gather_kernel<<<1024, 256, 0, stream>>>(wgt, vix, values, (float*)d_out);
  }
}

// Round 4
// 452.832 us; speedup vs baseline: 4.1610x; 1.0047x over previous
//
#include <hip/hip_runtime.h>
#include <math.h>

#define DQ 2048
#define CDIM 512
#define NKEYS 256
#define KSEL 32

__device__ __forceinline__ bool rank_before(float as, int ai, float bs, int bi) {
  return (as > bs) || (as == bs && ai < bi);
}
static __device__ __forceinline__ float bf2f(unsigned int u) {
  union { unsigned int i; float f; } v; v.i = u << 16; return v.f;
}
static __device__ __forceinline__ unsigned int f2bf(float f) {
  union { float f; unsigned int i; } v; v.f = f;
  unsigned int r = v.i + 0x7fffu + ((v.i >> 16) & 1u);
  return r >> 16;
}

// ---------------- q = LN(X * Wq^T) fused (fp32 vector GEMM + groupwise LN) ----------------
__global__ __launch_bounds__(256) void qgemm_ln(
    const float* __restrict__ X, const float* __restrict__ W,
    const float* __restrict__ gamma, const float* __restrict__ beta,
    float* __restrict__ Q) {
  __shared__ float As[16 * 68];   // [k][m]
  __shared__ float Bs[16 * 132];  // [k][n]
  const int tid = threadIdx.x;
  const int m0 = blockIdx.x * 64, n0 = blockIdx.y * 128;
  const int tx = tid & 15, ty = tid >> 4;
  const int am = tid >> 2, ak = (tid & 3) * 4;
  const int bn = tid >> 1, bk = (tid & 1) * 8;
  float acc[4][8] = {};
  // software prefetch of first tile
  float4 av  = *(const float4*)&X[(size_t)(m0 + am) * CDIM + ak];
  float4 bv0 = *(const float4*)&W[(size_t)(n0 + bn) * CDIM + bk];
  float4 bv1 = *(const float4*)&W[(size_t)(n0 + bn) * CDIM + bk + 4];
  for (int kt = 0; kt < CDIM; kt += 16) {
    __syncthreads();
    As[(ak + 0) * 68 + am] = av.x; As[(ak + 1) * 68 + am] = av.y;
    As[(ak + 2) * 68 + am] = av.z; As[(ak + 3) * 68 + am] = av.w;
    Bs[(bk + 0) * 132 + bn] = bv0.x; Bs[(bk + 1) * 132 + bn] = bv0.y;
    Bs[(bk + 2) * 132 + bn] = bv0.z; Bs[(bk + 3) * 132 + bn] = bv0.w;
    Bs[(bk + 4) * 132 + bn] = bv1.x; Bs[(bk + 5) * 132 + bn] = bv1.y;
    Bs[(bk + 6) * 132 + bn] = bv1.z; Bs[(bk + 7) * 132 + bn] = bv1.w;
    __syncthreads();
    if (kt + 16 < CDIM) {  // prefetch next tile; latency hides behind compute
      av  = *(const float4*)&X[(size_t)(m0 + am) * CDIM + kt + 16 + ak];
      bv0 = *(const float4*)&W[(size_t)(n0 + bn) * CDIM + kt + 16 + bk];
      bv1 = *(const float4*)&W[(size_t)(n0 + bn) * CDIM + kt + 16 + bk + 4];
    }
    #pragma unroll
    for (int kk = 0; kk < 16; ++kk) {
      float4 a4  = *(const float4*)&As[kk * 68 + ty * 4];
      float4 b4a = *(const float4*)&Bs[kk * 132 + tx * 8];
      float4 b4b = *(const float4*)&Bs[kk * 132 + tx * 8 + 4];
      const float ar[4] = {a4.x, a4.y, a4.z, a4.w};
      const float br[8] = {b4a.x, b4a.y, b4a.z, b4a.w, b4b.x, b4b.y, b4b.z, b4b.w};
      #pragma unroll
      for (int i = 0; i < 4; ++i)
        #pragma unroll
        for (int j = 0; j < 8; ++j)
          acc[i][j] += ar[i] * br[j];
    }
  }
  float g[8], bta[8];
  #pragma unroll
  for (int j = 0; j < 8; ++j) { g[j] = gamma[tx * 8 + j]; bta[j] = beta[tx * 8 + j]; }
  #pragma unroll
  for (int i = 0; i < 4; ++i) {
    float s = 0.f, sq = 0.f;
    #pragma unroll
    for (int j = 0; j < 8; ++j) { s += acc[i][j]; sq += acc[i][j] * acc[i][j]; }
    #pragma unroll
    for (int m = 1; m < 16; m <<= 1) {
      s += __shfl_xor(s, m, 64);
      sq += __shfl_xor(sq, m, 64);
    }
    float mean = s * (1.0f / 128.0f);
    float var = sq * (1.0f / 128.0f) - mean * mean;
    float rs = 1.0f / sqrtf(var + 1e-5f);
    float o[8];
    #pragma unroll
    for (int j = 0; j < 8; ++j) o[j] = (acc[i][j] - mean) * rs * g[j] + bta[j];
    float* dst = &Q[(size_t)(m0 + ty * 4 + i) * DQ + n0 + tx * 8];
    *(float4*)dst = make_float4(o[0], o[1], o[2], o[3]);
    *(float4*)(dst + 4) = make_float4(o[4], o[5], o[6], o[7]);
  }
}

// ---------------- keys[h][n][p][d] -> keysT[hp][d][n] (one-time, 2 MB) ----------------
// d-major layout lets dots_sel read the B operand straight from global, fully
// coalesced (64 lanes x float4 = one 256-key row per instruction), L2-resident.
// LDS 64x129 tile: coalesced global read AND coalesced global write.
__global__ __launch_bounds__(256) void transpose_keys(
    const float* __restrict__ keys, float* __restrict__ keysT) {
  __shared__ float tile[64 * 129];
  const int hp = blockIdx.x, h = hp >> 1, p = hp & 1;
  const int n0 = blockIdx.y * 64;
  {
    const int n = threadIdx.x >> 2;          // 0..63
    const int d0 = (threadIdx.x & 3) * 32;   // 0,32,64,96
    const float* src = &keys[(((size_t)h * NKEYS + n0 + n) * 2 + p) * 128 + d0];
    #pragma unroll
    for (int j = 0; j < 32; j += 4) {
      float4 v = *(const float4*)(src + j);
      tile[n * 129 + d0 + j + 0] = v.x;
      tile[n * 129 + d0 + j + 1] = v.y;
      tile[n * 129 + d0 + j + 2] = v.z;
      tile[n * 129 + d0 + j + 3] = v.w;
    }
  }
  __syncthreads();
  {
    const int d = threadIdx.x >> 1;          // 0..127
    const int nh = (threadIdx.x & 1) * 32;   // 0,32
    float* dst = &keysT[((size_t)hp * 128 + d) * NKEYS + n0 + nh];
    #pragma unroll
    for (int j = 0; j < 32; j += 4) {
      float4 o = make_float4(tile[(nh + j + 0) * 129 + d], tile[(nh + j + 1) * 129 + d],
                             tile[(nh + j + 2) * 129 + d], tile[(nh + j + 3) * 129 + d]);
      *(float4*)(dst + j) = o;
    }
  }
}

// ---------------- dots (Q from LDS, keysT direct from global/L2) + paired bitonic top-32 ----
// Round-4 structure: B (keys) is NOT staged in LDS. With keysT[hp][d][n], each
// lane's float4 at n=lane*4 makes one coalesced 1KB wave-load per d; the slice
// (128 KB per hp) is L2-hot across the 64 chunk-blocks. This removes the Bs
// array, its 8-way-aliased ds_read_b128s (the 1.18M bank-conflict source), and
// ALL K-loop barriers (one barrier total, after Qs staging). DS pipe now carries
// only wave-uniform A broadcasts + the sort shuffles.
// Sort = round-3 paired network (2 concurrent sorts; blocked-layout variant
// regressed in rounds 1-2, do not revisit). launch_bounds (512,5): cap ~102
// VGPRs; (512,6)'s 80-cap demoted sort state to scratch in round 1.
__global__ __launch_bounds__(512, 5) void dots_sel(
    const float* __restrict__ Q, const float* __restrict__ keysT,
    float* __restrict__ s1s, int* __restrict__ s1i) {
  const int hp = blockIdx.x;
  const int chunk = blockIdx.y;
  const int h = hp >> 1, p = hp & 1;
  const int t0 = chunk * 32;
  __shared__ float Qs[32 * 132];
  const int tid = threadIdx.x;
  const int w = tid >> 6, lane = tid & 63;
  {
    const int tok = tid >> 4, d0 = (tid & 15) * 8;
    const float* src = &Q[(size_t)(t0 + tok) * DQ + p * 1024 + h * 128 + d0];
    *(float4*)&Qs[tok * 132 + d0] = *(const float4*)src;
    *(float4*)&Qs[tok * 132 + d0 + 4] = *(const float4*)(src + 4);
  }
  __syncthreads();  // the only barrier in this kernel
  const float* kT = keysT + (size_t)hp * 128 * NKEYS + lane * 4;
  float acc[4][4] = {};
  #pragma unroll 2
  for (int kt = 0; kt < 128; kt += 4) {
    float4 a0 = *(const float4*)&Qs[(w * 4 + 0) * 132 + kt];
    float4 a1 = *(const float4*)&Qs[(w * 4 + 1) * 132 + kt];
    float4 a2 = *(const float4*)&Qs[(w * 4 + 2) * 132 + kt];
    float4 a3 = *(const float4*)&Qs[(w * 4 + 3) * 132 + kt];
    const float a0r[4] = {a0.x, a0.y, a0.z, a0.w};
    const float a1r[4] = {a1.x, a1.y, a1.z, a1.w};
    const float a2r[4] = {a2.x, a2.y, a2.z, a2.w};
    const float a3r[4] = {a3.x, a3.y, a3.z, a3.w};
    #pragma unroll
    for (int kk = 0; kk < 4; ++kk) {
      float4 b4 = *(const float4*)&kT[(size_t)(kt + kk) * NKEYS];
      const float br[4] = {b4.x, b4.y, b4.z, b4.w};
      #pragma unroll
      for (int j = 0; j < 4; ++j) {
        acc[0][j] += a0r[kk] * br[j];
        acc[1][j] += a1r[kk] * br[j];
        acc[2][j] += a2r[kk] * br[j];
        acc[3][j] += a3r[kk] * br[j];
      }
    }
  }
  // ---- paired in-register bitonic top-32 (2 concurrent sorts per iteration)
  #define CE1(S, I, a, b, dd)                                                  \
    {                                                                          \
      bool sw_ = (dd) ? rank_before(S[a], I[a], S[b], I[b])                    \
                      : rank_before(S[b], I[b], S[a], I[a]);                   \
      if (sw_) {                                                               \
        float ts_ = S[a]; S[a] = S[b]; S[b] = ts_;                             \
        int ti_ = I[a]; I[a] = I[b]; I[b] = ti_;                               \
      }                                                                        \
    }
  #define CEP(a, b, dd) { CE1(sA, iA, a, b, dd) CE1(sB, iB, a, b, dd) }
  #define CROSSP(L, dd)                                                        \
    {                                                                          \
      bool amHigh = (lane & (L)) != 0;                                         \
      bool flip = amHigh != (dd);                                              \
      _Pragma("unroll")                                                        \
      for (int r = 0; r < 4; ++r) {                                            \
        float osA = __shfl_xor(sA[r], (L), 64);                                \
        int oiA = __shfl_xor(iA[r], (L), 64);                                  \
        float osB = __shfl_xor(sB[r], (L), 64);                                \
        int oiB = __shfl_xor(iB[r], (L), 64);                                  \
        bool tA = rank_before(osA, oiA, sA[r], iA[r]) != flip;                 \
        if (tA) { sA[r] = osA; iA[r] = oiA; }                                  \
        bool tB = rank_before(osB, oiB, sB[r], iB[r]) != flip;                 \
        if (tB) { sB[r] = osB; iB[r] = oiB; }                                  \
      }                                                                        \
    }
  #pragma unroll
  for (int ii = 0; ii < 4; ii += 2) {  // fully unrolled: acc indexing stays static
    float sA[4], sB[4]; int iA[4], iB[4];
    #pragma unroll
    for (int r = 0; r < 4; ++r) {
      sA[r] = acc[ii][r];     iA[r] = lane * 4 + r;
      sB[r] = acc[ii + 1][r]; iB[r] = lane * 4 + r;
    }
    CEP(0, 1, false); CEP(2, 3, true);
    {
      bool dd = (lane & 1) != 0;
      CEP(0, 2, dd); CEP(1, 3, dd); CEP(0, 1, dd); CEP(2, 3, dd);
    }
    #pragma unroll
    for (int K = 8; K <= 256; K <<= 1) {
      bool dd = (lane & (K >> 2)) != 0;
      #pragma unroll
      for (int L = K >> 3; L >= 1; L >>= 1) CROSSP(L, dd);
      CEP(0, 2, dd); CEP(1, 3, dd); CEP(0, 1, dd); CEP(2, 3, dd);
    }
    const int instA = (t0 + w * 4 + ii) * 16 + hp;
    const int instB = instA + 16;  // token ii+1
    if (lane < 8) {
      *(float4*)&s1s[(size_t)instA * KSEL + lane * 4] = make_float4(sA[0], sA[1], sA[2], sA[3]);
      *(int4*)&s1i[(size_t)instA * KSEL + lane * 4] = make_int4(iA[0], iA[1], iA[2], iA[3]);
      *(float4*)&s1s[(size_t)instB * KSEL + lane * 4] = make_float4(sB[0], sB[1], sB[2], sB[3]);
      *(int4*)&s1i[(size_t)instB * KSEL + lane * 4] = make_int4(iB[0], iB[1], iB[2], iB[3]);
    }
  }
  #undef CE1
  #undef CEP
  #undef CROSSP
}

// ---------------- stage-2: pruned 119-candidate bitonic top-32 + softmax ----------------
__constant__ unsigned short slot_ij[128] = {
  0,1,2,3,4,5,6,7,8,9,10,11,12,13,14,15,16,17,18,19,20,21,22,23,24,25,26,27,28,29,30,31,
  32,33,34,35,36,37,38,39,40,41,42,43,44,45,46,47,
  64,65,66,67,68,69,70,71,72,73,
  96,97,98,99,100,101,102,103,
  128,129,130,131,132,133,
  160,161,162,163,164,
  192,193,194,195,
  224,225,226,227,
  256,257,258,
  288,289,290,
  320,321, 352,353, 384,385, 416,417, 448,449, 480,481,
  512,544,576,608,640,672,704,736,768,800,832,864,896,928,960,992,
  0xFFFF,0xFFFF,0xFFFF,0xFFFF,0xFFFF,0xFFFF,0xFFFF,0xFFFF,0xFFFF
};

__global__ __launch_bounds__(256) void stage2_kernel(
    const float* __restrict__ s1s, const int* __restrict__ s1i,
    float* __restrict__ wgt, int* __restrict__ vidx) {
  const int th = blockIdx.x * 4 + (threadIdx.x >> 6);
  const int lane = threadIdx.x & 63;
  const int bx = th * 64;
  const int by = bx + 32;
  float s[2]; int id[2];
  #pragma unroll
  for (int r = 0; r < 2; ++r) {
    int sl = slot_ij[lane * 2 + r];
    if (sl != 0xFFFF) {
      s[r] = s1s[bx + (sl >> 5)] + s1s[by + (sl & 31)];
      id[r] = sl;
    } else {
      s[r] = -INFINITY; id[r] = 0x7fffffff;
    }
  }
  #define CE2(dd)                                                              \
    {                                                                          \
      bool sw = (dd) ? rank_before(s[0], id[0], s[1], id[1])                   \
                     : rank_before(s[1], id[1], s[0], id[0]);                  \
      if (sw) {                                                                \
        float ts = s[0]; s[0] = s[1]; s[1] = ts;                               \
        int ti = id[0]; id[0] = id[1]; id[1] = ti;                             \
      }                                                                        \
    }
  #define CROSS2(L, dd)                                                        \
    {                                                                          \
      bool amHigh = (lane & (L)) != 0;                                         \
      bool flip = amHigh != (dd);                                              \
      _Pragma("unroll")                                                        \
      for (int r = 0; r < 2; ++r) {                                            \
        float os = __shfl_xor(s[r], (L), 64);                                  \
        int oi = __shfl_xor(id[r], (L), 64);                                   \
        bool take = rank_before(os, oi, s[r], id[r]) != flip;                  \
        if (take) { s[r] = os; id[r] = oi; }                                   \
      }                                                                        \
    }
  { bool dd = (lane & 1) != 0; CE2(dd); }
  #pragma unroll
  for (int K = 4; K <= 128; K <<= 1) {
    bool dd = (lane & (K >> 1)) != 0;
    #pragma unroll
    for (int L = K >> 2; L >= 1; L >>= 1) CROSS2(L, dd);
    CE2(dd);
  }
  #undef CE2
  #undef CROSS2
  float smax = __shfl(s[0], 0, 64);
  float e0 = 0.f, e1 = 0.f;
  if (lane < 16) { e0 = expf(s[0] - smax); e1 = expf(s[1] - smax); }
  float part = e0 + e1;
  #pragma unroll
  for (int m = 1; m < 16; m <<= 1) part += __shfl_xor(part, m, 64);
  if (lane < 16) {
    int f0 = id[0], f1 = id[1];
    int vi0 = s1i[bx + (f0 >> 5)] * NKEYS + s1i[by + (f0 & 31)];
    int vi1 = s1i[bx + (f1 >> 5)] * NKEYS + s1i[by + (f1 & 31)];
    wgt[(size_t)th * KSEL + lane * 2] = e0 / part;
    wgt[(size_t)th * KSEL + lane * 2 + 1] = e1 / part;
    vidx[(size_t)th * KSEL + lane * 2] = vi0;
    vidx[(size_t)th * KSEL + lane * 2 + 1] = vi1;
  }
}

// ---------------- values fp32 -> bf16 (RNE) one-pass convert ----------------
__global__ __launch_bounds__(256) void convert_values(
    const float* __restrict__ values, unsigned int* __restrict__ vbf) {
  const size_t g = ((size_t)blockIdx.x * 256 + threadIdx.x) * 8;
  float4 a = *(const float4*)(values + g);
  float4 b = *(const float4*)(values + g + 4);
  uint4 pk;
  pk.x = f2bf(a.x) | (f2bf(a.y) << 16);
  pk.y = f2bf(a.z) | (f2bf(a.w) << 16);
  pk.z = f2bf(b.x) | (f2bf(b.y) << 16);
  pk.w = f2bf(b.z) | (f2bf(b.w) << 16);
  *(uint4*)(vbf + g / 2) = pk;
}

// ---------------- gather bf16: wave-per-row, 4 L3 phases ----------------
__global__ __launch_bounds__(256) void gather_bf16(
    const float* __restrict__ wgt, const int* __restrict__ vidx,
    const unsigned short* __restrict__ vbf, float* __restrict__ out) {
  const int t = blockIdx.x;
  const int tid = threadIdx.x, w = tid >> 6, lane = tid & 63;
  __shared__ float ws_[256];
  __shared__ int vs_[256];
  __shared__ float part[4 * 520];
  ws_[tid] = wgt[(size_t)t * 256 + tid];
  vs_[tid] = vidx[(size_t)t * 256 + tid];
  __syncthreads();
  float acc[8] = {};
  const int c0 = lane * 8;
  #pragma unroll 1
  for (int phase = 0; phase < 4; ++phase) {
    for (int e = w; e < 256; e += 4) {
      const int row = vs_[e];                 // wave-uniform scalar
      if ((row >> 14) != phase) continue;     // uniform branch, no divergence
      const float wv = ws_[e];
      uint4 pk = *(const uint4*)(vbf + (size_t)row * CDIM + c0);
      acc[0] += wv * bf2f(pk.x & 0xffff); acc[1] += wv * bf2f(pk.x >> 16);
      acc[2] += wv * bf2f(pk.y & 0xffff); acc[3] += wv * bf2f(pk.y >> 16);
      acc[4] += wv * bf2f(pk.z & 0xffff); acc[5] += wv * bf2f(pk.z >> 16);
      acc[6] += wv * bf2f(pk.w & 0xffff); acc[7] += wv * bf2f(pk.w >> 16);
    }
  }
  #pragma unroll
  for (int j = 0; j < 8; j += 4)
    *(float4*)&part[w * 520 + c0 + j] =
        make_float4(acc[j], acc[j + 1], acc[j + 2], acc[j + 3]);
  __syncthreads();
  const int c2 = tid * 2;
  float r0 = part[c2] + part[520 + c2] + part[1040 + c2] + part[1560 + c2];
  float r1 = part[c2 + 1] + part[520 + c2 + 1] + part[1040 + c2 + 1] + part[1560 + c2 + 1];
  *(float2*)(out + (size_t)t * CDIM + c2) = make_float2(r0, r1);
}

// ---------------- fallback fp32 gather (round-4, for small ws) ----------------
__global__ __launch_bounds__(256) void gather_kernel(
    const float* __restrict__ wgt, const int* __restrict__ vidx,
    const float* __restrict__ values, float* __restrict__ out) {
  const int tp = blockIdx.x;
  const int tid = threadIdx.x;
  __shared__ float ws_[512];
  __shared__ int vs_[512];
  ws_[tid] = wgt[(size_t)tp * 512 + tid];
  ws_[tid + 256] = wgt[(size_t)tp * 512 + tid + 256];
  vs_[tid] = vidx[(size_t)tp * 512 + tid];
  vs_[tid + 256] = vidx[(size_t)tp * 512 + tid + 256];
  __syncthreads();
  const int sub = tid >> 7;
  const int c4 = (tid & 127) * 4;
  const float* wp = &ws_[sub * 256];
  const int* vp = &vs_[sub * 256];
  float4 a = make_float4(0.f, 0.f, 0.f, 0.f);
  #pragma unroll 4
  for (int e = 0; e < 256; ++e) {
    float4 vv = *(const float4*)(values + (size_t)vp[e] * CDIM + c4);
    float wv = wp[e];
    a.x += wv * vv.x; a.y += wv * vv.y; a.z += wv * vv.z; a.w += wv * vv.w;
  }
  *(float4*)(out + (size_t)(tp * 2 + sub) * CDIM + c4) = a;
}

extern "C" void kernel_launch(void* const* d_in, const int* in_sizes, int n_in,
                              void* d_out, int out_size, void* d_ws, size_t ws_size,
                              hipStream_t stream) {
  const float* X      = (const float*)d_in[0];
  const float* W      = (const float*)d_in[1];
  const float* keys   = (const float*)d_in[2];
  const float* values = (const float*)d_in[3];
  const float* gamma  = (const float*)d_in[4];
  const float* beta   = (const float*)d_in[5];
  char* ws = (char*)d_ws;
  float* s1s = (float*)(ws);                  // 0..4 MB
  int*   s1i = (int*)  (ws + (4u << 20));     // 4..8 MB
  float* wgt = (float*)(ws + (8u << 20));     // 8..10 MB
  int*   vix = (int*)  (ws + (10u << 20));    // 10..12 MB
  float* Q   = (float*)(ws + (12u << 20));    // 12..28 MB (dead after dots_sel)
  float* kT  = (float*)(ws + (28u << 20));    // 28..30 MB (dead after dots_sel)
  unsigned int* vbf = (unsigned int*)(ws + (12u << 20));  // 12..76 MB (overlaps dead Q+kT)

  const bool bf16_path = ws_size >= (76u << 20);

  transpose_keys<<<dim3(16, 4), 256, 0, stream>>>(keys, kT);
  qgemm_ln<<<dim3(32, 16), 256, 0, stream>>>(X, W, gamma, beta, Q);
  dots_sel<<<dim3(16, 64), 512, 0, stream>>>(Q, kT, s1s, s1i);
  stage2_kernel<<<4096, 256, 0, stream>>>(s1s, s1i, wgt, vix);
  if (bf16_path) {
    convert_values<<<16384, 256, 0, stream>>>(values, vbf);  // after dots_sel: Q,kT dead
    gather_bf16<<<2048, 256, 0, stream>>>(wgt, vix, (const unsigned short*)vbf, (float*)d_out);
  } else {
    gather_kernel<<<1024, 256, 0, stream>>>(wgt, vix, values, (float*)d_out);
  }
}

// Round 5
// 439.799 us; speedup vs baseline: 4.2843x; 1.0296x over previous
//
#include <hip/hip_runtime.h>
#include <math.h>

#define DQ 2048
#define CDIM 512
#define NKEYS 256
#define KSEL 32

__device__ __forceinline__ bool rank_before(float as, int ai, float bs, int bi) {
  return (as > bs) || (as == bs && ai < bi);
}
static __device__ __forceinline__ float bf2f(unsigned int u) {
  union { unsigned int i; float f; } v; v.i = u << 16; return v.f;
}
static __device__ __forceinline__ unsigned int f2bf(float f) {
  union { float f; unsigned int i; } v; v.f = f;
  unsigned int r = v.i + 0x7fffu + ((v.i >> 16) & 1u);
  return r >> 16;
}

// ---------------- q = LN(X * Wq^T) fused (fp32 vector GEMM + groupwise LN) ----------------
__global__ __launch_bounds__(256) void qgemm_ln(
    const float* __restrict__ X, const float* __restrict__ W,
    const float* __restrict__ gamma, const float* __restrict__ beta,
    float* __restrict__ Q) {
  __shared__ float As[16 * 68];   // [k][m]
  __shared__ float Bs[16 * 132];  // [k][n]
  const int tid = threadIdx.x;
  const int m0 = blockIdx.x * 64, n0 = blockIdx.y * 128;
  const int tx = tid & 15, ty = tid >> 4;
  const int am = tid >> 2, ak = (tid & 3) * 4;
  const int bn = tid >> 1, bk = (tid & 1) * 8;
  float acc[4][8] = {};
  // software prefetch of first tile
  float4 av  = *(const float4*)&X[(size_t)(m0 + am) * CDIM + ak];
  float4 bv0 = *(const float4*)&W[(size_t)(n0 + bn) * CDIM + bk];
  float4 bv1 = *(const float4*)&W[(size_t)(n0 + bn) * CDIM + bk + 4];
  for (int kt = 0; kt < CDIM; kt += 16) {
    __syncthreads();
    As[(ak + 0) * 68 + am] = av.x; As[(ak + 1) * 68 + am] = av.y;
    As[(ak + 2) * 68 + am] = av.z; As[(ak + 3) * 68 + am] = av.w;
    Bs[(bk + 0) * 132 + bn] = bv0.x; Bs[(bk + 1) * 132 + bn] = bv0.y;
    Bs[(bk + 2) * 132 + bn] = bv0.z; Bs[(bk + 3) * 132 + bn] = bv0.w;
    Bs[(bk + 4) * 132 + bn] = bv1.x; Bs[(bk + 5) * 132 + bn] = bv1.y;
    Bs[(bk + 6) * 132 + bn] = bv1.z; Bs[(bk + 7) * 132 + bn] = bv1.w;
    __syncthreads();
    if (kt + 16 < CDIM) {  // prefetch next tile; latency hides behind compute
      av  = *(const float4*)&X[(size_t)(m0 + am) * CDIM + kt + 16 + ak];
      bv0 = *(const float4*)&W[(size_t)(n0 + bn) * CDIM + kt + 16 + bk];
      bv1 = *(const float4*)&W[(size_t)(n0 + bn) * CDIM + kt + 16 + bk + 4];
    }
    #pragma unroll
    for (int kk = 0; kk < 16; ++kk) {
      float4 a4  = *(const float4*)&As[kk * 68 + ty * 4];
      float4 b4a = *(const float4*)&Bs[kk * 132 + tx * 8];
      float4 b4b = *(const float4*)&Bs[kk * 132 + tx * 8 + 4];
      const float ar[4] = {a4.x, a4.y, a4.z, a4.w};
      const float br[8] = {b4a.x, b4a.y, b4a.z, b4a.w, b4b.x, b4b.y, b4b.z, b4b.w};
      #pragma unroll
      for (int i = 0; i < 4; ++i)
        #pragma unroll
        for (int j = 0; j < 8; ++j)
          acc[i][j] += ar[i] * br[j];
    }
  }
  float g[8], bta[8];
  #pragma unroll
  for (int j = 0; j < 8; ++j) { g[j] = gamma[tx * 8 + j]; bta[j] = beta[tx * 8 + j]; }
  #pragma unroll
  for (int i = 0; i < 4; ++i) {
    float s = 0.f, sq = 0.f;
    #pragma unroll
    for (int j = 0; j < 8; ++j) { s += acc[i][j]; sq += acc[i][j] * acc[i][j]; }
    #pragma unroll
    for (int m = 1; m < 16; m <<= 1) {
      s += __shfl_xor(s, m, 64);
      sq += __shfl_xor(sq, m, 64);
    }
    float mean = s * (1.0f / 128.0f);
    float var = sq * (1.0f / 128.0f) - mean * mean;
    float rs = 1.0f / sqrtf(var + 1e-5f);
    float o[8];
    #pragma unroll
    for (int j = 0; j < 8; ++j) o[j] = (acc[i][j] - mean) * rs * g[j] + bta[j];
    float* dst = &Q[(size_t)(m0 + ty * 4 + i) * DQ + n0 + tx * 8];
    *(float4*)dst = make_float4(o[0], o[1], o[2], o[3]);
    *(float4*)(dst + 4) = make_float4(o[4], o[5], o[6], o[7]);
  }
}

// ---------------- keys[h][n][p][d] -> keysT[hp][d][n] (one-time, 2 MB) ----------------
__global__ __launch_bounds__(256) void transpose_keys(
    const float* __restrict__ keys, float* __restrict__ keysT) {
  __shared__ float tile[64 * 129];
  const int hp = blockIdx.x, h = hp >> 1, p = hp & 1;
  const int n0 = blockIdx.y * 64;
  {
    const int n = threadIdx.x >> 2;          // 0..63
    const int d0 = (threadIdx.x & 3) * 32;   // 0,32,64,96
    const float* src = &keys[(((size_t)h * NKEYS + n0 + n) * 2 + p) * 128 + d0];
    #pragma unroll
    for (int j = 0; j < 32; j += 4) {
      float4 v = *(const float4*)(src + j);
      tile[n * 129 + d0 + j + 0] = v.x;
      tile[n * 129 + d0 + j + 1] = v.y;
      tile[n * 129 + d0 + j + 2] = v.z;
      tile[n * 129 + d0 + j + 3] = v.w;
    }
  }
  __syncthreads();
  {
    const int d = threadIdx.x >> 1;          // 0..127
    const int nh = (threadIdx.x & 1) * 32;   // 0,32
    float* dst = &keysT[((size_t)hp * 128 + d) * NKEYS + n0 + nh];
    #pragma unroll
    for (int j = 0; j < 32; j += 4) {
      float4 o = make_float4(tile[(nh + j + 0) * 129 + d], tile[(nh + j + 1) * 129 + d],
                             tile[(nh + j + 2) * 129 + d], tile[(nh + j + 3) * 129 + d]);
      *(float4*)(dst + j) = o;
    }
  }
}

// ---------------- dots (A uniform from global/SMEM, B coalesced from global/L2) ----------
// Round-5 structure: NO LDS AT ALL in this kernel. The A operand (Q rows) is
// wave-uniform -> the old Qs staging was just a broadcast through the DS pipe
// (4096 ds_read_b128/CU ~= 20 us of DS occupancy). Reading it directly from
// global with a readfirstlane-uniformed pointer lets LLVM select scalar s_load
// (SMEM pipe; worst case a VMEM broadcast) -- either way the DS pipe now
// carries ONLY the sort shuffles. Zero barriers; occupancy capped only by
// VGPRs. B reads (keysT d-major) stay coalesced 1KB wave-loads, L2-hot.
// Sort = round-3 paired network (2 concurrent sorts). Blocked-layout sort
// regressed (rounds 1-2); (512,6) launch-bounds demoted state to scratch
// (round 1) -- keep (512,5).
__global__ __launch_bounds__(512, 5) void dots_sel(
    const float* __restrict__ Q, const float* __restrict__ keysT,
    float* __restrict__ s1s, int* __restrict__ s1i) {
  const int hp = blockIdx.x;
  const int chunk = blockIdx.y;
  const int h = hp >> 1, p = hp & 1;
  const int t0 = chunk * 32;
  const int tid = threadIdx.x;
  const int w = tid >> 6, lane = tid & 63;
  // wave-uniform Q row pointers (readfirstlane -> provably uniform -> SMEM)
  const int wu = __builtin_amdgcn_readfirstlane(w);
  const float* q0 = &Q[(size_t)(t0 + wu * 4 + 0) * DQ + p * 1024 + h * 128];
  const float* q1 = q0 + DQ;
  const float* q2 = q0 + 2 * DQ;
  const float* q3 = q0 + 3 * DQ;
  const float* kT = keysT + (size_t)hp * 128 * NKEYS + lane * 4;
  float acc[4][4] = {};
  #pragma unroll 2
  for (int kt = 0; kt < 128; kt += 4) {
    float4 a0 = *(const float4*)&q0[kt];
    float4 a1 = *(const float4*)&q1[kt];
    float4 a2 = *(const float4*)&q2[kt];
    float4 a3 = *(const float4*)&q3[kt];
    const float a0r[4] = {a0.x, a0.y, a0.z, a0.w};
    const float a1r[4] = {a1.x, a1.y, a1.z, a1.w};
    const float a2r[4] = {a2.x, a2.y, a2.z, a2.w};
    const float a3r[4] = {a3.x, a3.y, a3.z, a3.w};
    #pragma unroll
    for (int kk = 0; kk < 4; ++kk) {
      float4 b4 = *(const float4*)&kT[(size_t)(kt + kk) * NKEYS];
      const float br[4] = {b4.x, b4.y, b4.z, b4.w};
      #pragma unroll
      for (int j = 0; j < 4; ++j) {
        acc[0][j] += a0r[kk] * br[j];
        acc[1][j] += a1r[kk] * br[j];
        acc[2][j] += a2r[kk] * br[j];
        acc[3][j] += a3r[kk] * br[j];
      }
    }
  }
  // ---- paired in-register bitonic top-32 (2 concurrent sorts per iteration)
  #define CE1(S, I, a, b, dd)                                                  \
    {                                                                          \
      bool sw_ = (dd) ? rank_before(S[a], I[a], S[b], I[b])                    \
                      : rank_before(S[b], I[b], S[a], I[a]);                   \
      if (sw_) {                                                               \
        float ts_ = S[a]; S[a] = S[b]; S[b] = ts_;                             \
        int ti_ = I[a]; I[a] = I[b]; I[b] = ti_;                               \
      }                                                                        \
    }
  #define CEP(a, b, dd) { CE1(sA, iA, a, b, dd) CE1(sB, iB, a, b, dd) }
  #define CROSSP(L, dd)                                                        \
    {                                                                          \
      bool amHigh = (lane & (L)) != 0;                                         \
      bool flip = amHigh != (dd);                                              \
      _Pragma("unroll")                                                        \
      for (int r = 0; r < 4; ++r) {                                            \
        float osA = __shfl_xor(sA[r], (L), 64);                                \
        int oiA = __shfl_xor(iA[r], (L), 64);                                  \
        float osB = __shfl_xor(sB[r], (L), 64);                                \
        int oiB = __shfl_xor(iB[r], (L), 64);                                  \
        bool tA = rank_before(osA, oiA, sA[r], iA[r]) != flip;                 \
        if (tA) { sA[r] = osA; iA[r] = oiA; }                                  \
        bool tB = rank_before(osB, oiB, sB[r], iB[r]) != flip;                 \
        if (tB) { sB[r] = osB; iB[r] = oiB; }                                  \
      }                                                                        \
    }
  #pragma unroll
  for (int ii = 0; ii < 4; ii += 2) {  // fully unrolled: acc indexing stays static
    float sA[4], sB[4]; int iA[4], iB[4];
    #pragma unroll
    for (int r = 0; r < 4; ++r) {
      sA[r] = acc[ii][r];     iA[r] = lane * 4 + r;
      sB[r] = acc[ii + 1][r]; iB[r] = lane * 4 + r;
    }
    CEP(0, 1, false); CEP(2, 3, true);
    {
      bool dd = (lane & 1) != 0;
      CEP(0, 2, dd); CEP(1, 3, dd); CEP(0, 1, dd); CEP(2, 3, dd);
    }
    #pragma unroll
    for (int K = 8; K <= 256; K <<= 1) {
      bool dd = (lane & (K >> 2)) != 0;
      #pragma unroll
      for (int L = K >> 3; L >= 1; L >>= 1) CROSSP(L, dd);
      CEP(0, 2, dd); CEP(1, 3, dd); CEP(0, 1, dd); CEP(2, 3, dd);
    }
    const int instA = (t0 + w * 4 + ii) * 16 + hp;
    const int instB = instA + 16;  // token ii+1
    if (lane < 8) {
      *(float4*)&s1s[(size_t)instA * KSEL + lane * 4] = make_float4(sA[0], sA[1], sA[2], sA[3]);
      *(int4*)&s1i[(size_t)instA * KSEL + lane * 4] = make_int4(iA[0], iA[1], iA[2], iA[3]);
      *(float4*)&s1s[(size_t)instB * KSEL + lane * 4] = make_float4(sB[0], sB[1], sB[2], sB[3]);
      *(int4*)&s1i[(size_t)instB * KSEL + lane * 4] = make_int4(iB[0], iB[1], iB[2], iB[3]);
    }
  }
  #undef CE1
  #undef CEP
  #undef CROSSP
}

// ---------------- stage-2: pruned 119-candidate bitonic top-32 + softmax ----------------
__constant__ unsigned short slot_ij[128] = {
  0,1,2,3,4,5,6,7,8,9,10,11,12,13,14,15,16,17,18,19,20,21,22,23,24,25,26,27,28,29,30,31,
  32,33,34,35,36,37,38,39,40,41,42,43,44,45,46,47,
  64,65,66,67,68,69,70,71,72,73,
  96,97,98,99,100,101,102,103,
  128,129,130,131,132,133,
  160,161,162,163,164,
  192,193,194,195,
  224,225,226,227,
  256,257,258,
  288,289,290,
  320,321, 352,353, 384,385, 416,417, 448,449, 480,481,
  512,544,576,608,640,672,704,736,768,800,832,864,896,928,960,992,
  0xFFFF,0xFFFF,0xFFFF,0xFFFF,0xFFFF,0xFFFF,0xFFFF,0xFFFF,0xFFFF
};

__global__ __launch_bounds__(256) void stage2_kernel(
    const float* __restrict__ s1s, const int* __restrict__ s1i,
    float* __restrict__ wgt, int* __restrict__ vidx) {
  const int th = blockIdx.x * 4 + (threadIdx.x >> 6);
  const int lane = threadIdx.x & 63;
  const int bx = th * 64;
  const int by = bx + 32;
  float s[2]; int id[2];
  #pragma unroll
  for (int r = 0; r < 2; ++r) {
    int sl = slot_ij[lane * 2 + r];
    if (sl != 0xFFFF) {
      s[r] = s1s[bx + (sl >> 5)] + s1s[by + (sl & 31)];
      id[r] = sl;
    } else {
      s[r] = -INFINITY; id[r] = 0x7fffffff;
    }
  }
  #define CE2(dd)                                                              \
    {                                                                          \
      bool sw = (dd) ? rank_before(s[0], id[0], s[1], id[1])                   \
                     : rank_before(s[1], id[1], s[0], id[0]);                  \
      if (sw) {                                                                \
        float ts = s[0]; s[0] = s[1]; s[1] = ts;                               \
        int ti = id[0]; id[0] = id[1]; id[1] = ti;                             \
      }                                                                        \
    }
  #define CROSS2(L, dd)                                                        \
    {                                                                          \
      bool amHigh = (lane & (L)) != 0;                                         \
      bool flip = amHigh != (dd);                                              \
      _Pragma("unroll")                                                        \
      for (int r = 0; r < 2; ++r) {                                            \
        float os = __shfl_xor(s[r], (L), 64);                                  \
        int oi = __shfl_xor(id[r], (L), 64);                                   \
        bool take = rank_before(os, oi, s[r], id[r]) != flip;                  \
        if (take) { s[r] = os; id[r] = oi; }                                   \
      }                                                                        \
    }
  { bool dd = (lane & 1) != 0; CE2(dd); }
  #pragma unroll
  for (int K = 4; K <= 128; K <<= 1) {
    bool dd = (lane & (K >> 1)) != 0;
    #pragma unroll
    for (int L = K >> 2; L >= 1; L >>= 1) CROSS2(L, dd);
    CE2(dd);
  }
  #undef CE2
  #undef CROSS2
  float smax = __shfl(s[0], 0, 64);
  float e0 = 0.f, e1 = 0.f;
  if (lane < 16) { e0 = expf(s[0] - smax); e1 = expf(s[1] - smax); }
  float part = e0 + e1;
  #pragma unroll
  for (int m = 1; m < 16; m <<= 1) part += __shfl_xor(part, m, 64);
  if (lane < 16) {
    int f0 = id[0], f1 = id[1];
    int vi0 = s1i[bx + (f0 >> 5)] * NKEYS + s1i[by + (f0 & 31)];
    int vi1 = s1i[bx + (f1 >> 5)] * NKEYS + s1i[by + (f1 & 31)];
    wgt[(size_t)th * KSEL + lane * 2] = e0 / part;
    wgt[(size_t)th * KSEL + lane * 2 + 1] = e1 / part;
    vidx[(size_t)th * KSEL + lane * 2] = vi0;
    vidx[(size_t)th * KSEL + lane * 2 + 1] = vi1;
  }
}

// ---------------- values fp32 -> bf16 (RNE) one-pass convert ----------------
__global__ __launch_bounds__(256) void convert_values(
    const float* __restrict__ values, unsigned int* __restrict__ vbf) {
  const size_t g = ((size_t)blockIdx.x * 256 + threadIdx.x) * 8;
  float4 a = *(const float4*)(values + g);
  float4 b = *(const float4*)(values + g + 4);
  uint4 pk;
  pk.x = f2bf(a.x) | (f2bf(a.y) << 16);
  pk.y = f2bf(a.z) | (f2bf(a.w) << 16);
  pk.z = f2bf(b.x) | (f2bf(b.y) << 16);
  pk.w = f2bf(b.z) | (f2bf(b.w) << 16);
  *(uint4*)(vbf + g / 2) = pk;
}

// ---------------- gather bf16: wave-per-row, 4 L3 phases ----------------
__global__ __launch_bounds__(256) void gather_bf16(
    const float* __restrict__ wgt, const int* __restrict__ vidx,
    const unsigned short* __restrict__ vbf, float* __restrict__ out) {
  const int t = blockIdx.x;
  const int tid = threadIdx.x, w = tid >> 6, lane = tid & 63;
  __shared__ float ws_[256];
  __shared__ int vs_[256];
  __shared__ float part[4 * 520];
  ws_[tid] = wgt[(size_t)t * 256 + tid];
  vs_[tid] = vidx[(size_t)t * 256 + tid];
  __syncthreads();
  float acc[8] = {};
  const int c0 = lane * 8;
  #pragma unroll 1
  for (int phase = 0; phase < 4; ++phase) {
    for (int e = w; e < 256; e += 4) {
      const int row = vs_[e];                 // wave-uniform scalar
      if ((row >> 14) != phase) continue;     // uniform branch, no divergence
      const float wv = ws_[e];
      uint4 pk = *(const uint4*)(vbf + (size_t)row * CDIM + c0);
      acc[0] += wv * bf2f(pk.x & 0xffff); acc[1] += wv * bf2f(pk.x >> 16);
      acc[2] += wv * bf2f(pk.y & 0xffff); acc[3] += wv * bf2f(pk.y >> 16);
      acc[4] += wv * bf2f(pk.z & 0xffff); acc[5] += wv * bf2f(pk.z >> 16);
      acc[6] += wv * bf2f(pk.w & 0xffff); acc[7] += wv * bf2f(pk.w >> 16);
    }
  }
  #pragma unroll
  for (int j = 0; j < 8; j += 4)
    *(float4*)&part[w * 520 + c0 + j] =
        make_float4(acc[j], acc[j + 1], acc[j + 2], acc[j + 3]);
  __syncthreads();
  const int c2 = tid * 2;
  float r0 = part[c2] + part[520 + c2] + part[1040 + c2] + part[1560 + c2];
  float r1 = part[c2 + 1] + part[520 + c2 + 1] + part[1040 + c2 + 1] + part[1560 + c2 + 1];
  *(float2*)(out + (size_t)t * CDIM + c2) = make_float2(r0, r1);
}

// ---------------- fallback fp32 gather (round-4, for small ws) ----------------
__global__ __launch_bounds__(256) void gather_kernel(
    const float* __restrict__ wgt, const int* __restrict__ vidx,
    const float* __restrict__ values, float* __restrict__ out) {
  const int tp = blockIdx.x;
  const int tid = threadIdx.x;
  __shared__ float ws_[512];
  __shared__ int vs_[512];
  ws_[tid] = wgt[(size_t)tp * 512 + tid];
  ws_[tid + 256] = wgt[(size_t)tp * 512 + tid + 256];
  vs_[tid] = vidx[(size_t)tp * 512 + tid];
  vs_[tid + 256] = vidx[(size_t)tp * 512 + tid + 256];
  __syncthreads();
  const int sub = tid >> 7;
  const int c4 = (tid & 127) * 4;
  const float* wp = &ws_[sub * 256];
  const int* vp = &vs_[sub * 256];
  float4 a = make_float4(0.f, 0.f, 0.f, 0.f);
  #pragma unroll 4
  for (int e = 0; e < 256; ++e) {
    float4 vv = *(const float4*)(values + (size_t)vp[e] * CDIM + c4);
    float wv = wp[e];
    a.x += wv * vv.x; a.y += wv * vv.y; a.z += wv * vv.z; a.w += wv * vv.w;
  }
  *(float4*)(out + (size_t)(tp * 2 + sub) * CDIM + c4) = a;
}

extern "C" void kernel_launch(void* const* d_in, const int* in_sizes, int n_in,
                              void* d_out, int out_size, void* d_ws, size_t ws_size,
                              hipStream_t stream) {
  const float* X      = (const float*)d_in[0];
  const float* W      = (const float*)d_in[1];
  const float* keys   = (const float*)d_in[2];
  const float* values = (const float*)d_in[3];
  const float* gamma  = (const float*)d_in[4];
  const float* beta   = (const float*)d_in[5];
  char* ws = (char*)d_ws;
  float* s1s = (float*)(ws);                  // 0..4 MB
  int*   s1i = (int*)  (ws + (4u << 20));     // 4..8 MB
  float* wgt = (float*)(ws + (8u << 20));     // 8..10 MB
  int*   vix = (int*)  (ws + (10u << 20));    // 10..12 MB
  float* Q   = (float*)(ws + (12u << 20));    // 12..28 MB (dead after dots_sel)
  float* kT  = (float*)(ws + (28u << 20));    // 28..30 MB (dead after dots_sel)
  unsigned int* vbf = (unsigned int*)(ws + (12u << 20));  // 12..76 MB (overlaps dead Q+kT)

  const bool bf16_path = ws_size >= (76u << 20);

  transpose_keys<<<dim3(16, 4), 256, 0, stream>>>(keys, kT);
  qgemm_ln<<<dim3(32, 16), 256, 0, stream>>>(X, W, gamma, beta, Q);
  dots_sel<<<dim3(16, 64), 512, 0, stream>>>(Q, kT, s1s, s1i);
  stage2_kernel<<<4096, 256, 0, stream>>>(s1s, s1i, wgt, vix);
  if (bf16_path) {
    convert_values<<<16384, 256, 0, stream>>>(values, vbf);  // after dots_sel: Q,kT dead
    gather_bf16<<<2048, 256, 0, stream>>>(wgt, vix, (const unsigned short*)vbf, (float*)d_out);
  } else {
    gather_kernel<<<1024, 256, 0, stream>>>(wgt, vix, values, (float*)d_out);
  }
}